// Round 11
// baseline (122.928 us; speedup 1.0000x reference)
//
#include <hip/hip_runtime.h>
#include <math.h>

// Dims: x[64,512,28,28] -> out[64,544,28,28] fp32
static constexpr int BB    = 64;
static constexpr int C_IN  = 512;
static constexpr int C_MID = 128;
static constexpr int C_OUT = 32;
static constexpr int C_TOT = 544;
static constexpr int HW    = 784;   // 28*28

// ---- workspace layout (float offsets). ~27 MB ----
static constexpr size_t H2_OFF    = 0;                         // bf16 h2: 64*128*784 ushorts
static constexpr size_t QW1_OFF   = 6422528;                   // bf16 [8][128][64] swizzled
static constexpr size_t QW2_OFF   = QW1_OFF + 65536;           // bf16 [co32][k1152]
static constexpr size_t PSTAT_OFF = QW2_OFF + 49152;           // [512][8][4] {s,s2,mn,mx}
static constexpr size_t BNA_OFF   = PSTAT_OFF + 16384;         // 512
static constexpr size_t BNB_OFF   = BNA_OFF + 512;             // 512
static constexpr size_t A2_OFF    = BNB_OFF + 512;             // 128
static constexpr size_t B2_OFF    = A2_OFF + 128;
static constexpr size_t QRW_OFF   = B2_OFF + 128;
static constexpr size_t QRB_OFF   = QRW_OFF + 128;
static constexpr size_t SCAL_OFF  = QRB_OFF + 128;             // 16: 0=mn1 1=sc1 2=inv1 6=mx1
static constexpr size_t PART_OFF  = SCAL_OFF + 16;             // weight partials: w1[32][2], w2 at +64 [8][2]
static constexpr size_t RP_OFF    = PART_OFF + 128;            // rbn partials [co128][b64][pt7][3]
static constexpr size_t PART2_OFF = RP_OFF + 172032;           // per-channel h3 lo/hi [128][2]

#define DEVFN __device__ __forceinline__

typedef __bf16 bf16x8 __attribute__((ext_vector_type(8)));
typedef float  f32x4  __attribute__((ext_vector_type(4)));

DEVFN float qact(float v, float mn, float mx, float inv, float sc) {
    v = fminf(fmaxf(v, mn), mx);
    return fmaf(rintf((v - mn) * inv), sc, mn);   // rintf == round-half-even == jnp.round
}

DEVFN unsigned f2bf(float f) {                    // fp32 -> bf16 bits, RNE
    unsigned u = __float_as_uint(f);
    return (u + 0x7fffu + ((u >> 16) & 1u)) >> 16;
}

DEVFN float bf2f(unsigned short h) { return __uint_as_float((unsigned)h << 16); }

// ---------- K0: per-channel x stats (4096 blocks, channel-major) + weight partials (40) ----------
__global__ __launch_bounds__(256) void k_stats(const float* __restrict__ x,
                                               const float* __restrict__ conv1_w,
                                               const float* __restrict__ conv2_w,
                                               float* __restrict__ ws) {
    const int bid = blockIdx.x, tid = threadIdx.x;
    __shared__ float r0[256], r1[256], r2[256], r3[256];

    if (bid < 4096) {                              // x stats: (c, 8-image group)
        const int c = bid >> 3, bg = bid & 7;
        float s = 0.f, s2 = 0.f, mn = INFINITY, mx = -INFINITY;
        for (int i = tid; i < 1568; i += 256) {
            const int b = bg * 8 + i / 196, j = i % 196;
            const float4 v = ((const float4*)(x + ((size_t)b * C_IN + c) * HW))[j];
            s  += (v.x + v.y) + (v.z + v.w);
            s2 += v.x * v.x + v.y * v.y + v.z * v.z + v.w * v.w;
            mn = fminf(mn, fminf(fminf(v.x, v.y), fminf(v.z, v.w)));
            mx = fmaxf(mx, fmaxf(fmaxf(v.x, v.y), fmaxf(v.z, v.w)));
        }
        r0[tid] = s; r1[tid] = s2; r2[tid] = mn; r3[tid] = mx;
        __syncthreads();
        for (int off = 128; off > 0; off >>= 1) {
            if (tid < off) {
                r0[tid] += r0[tid + off];
                r1[tid] += r1[tid + off];
                r2[tid] = fminf(r2[tid], r2[tid + off]);
                r3[tid] = fmaxf(r3[tid], r3[tid + off]);
            }
            __syncthreads();
        }
        if (tid == 0) {
            float* p = ws + PSTAT_OFF + ((size_t)c * 8 + bg) * 4;
            p[0] = r0[0]; p[1] = r1[0]; p[2] = r2[0]; p[3] = r3[0];
        }
    } else {                                       // weight min/max -> fixed partial slots
        float mn = INFINITY, mx = -INFINITY;
        if (bid < 4128) {
            const float4* src = (const float4*)conv1_w + (size_t)(bid - 4096) * 512;
            for (int i = tid; i < 512; i += 256) {
                const float4 v = src[i];
                mn = fminf(mn, fminf(fminf(v.x, v.y), fminf(v.z, v.w)));
                mx = fmaxf(mx, fmaxf(fmaxf(v.x, v.y), fmaxf(v.z, v.w)));
            }
        } else {
            const float4* src = (const float4*)conv2_w + (size_t)(bid - 4128) * 1152;
            for (int i = tid; i < 1152; i += 256) {
                const float4 v = src[i];
                mn = fminf(mn, fminf(fminf(v.x, v.y), fminf(v.z, v.w)));
                mx = fmaxf(mx, fmaxf(fmaxf(v.x, v.y), fmaxf(v.z, v.w)));
            }
        }
        r2[tid] = mn; r3[tid] = mx;
        __syncthreads();
        for (int off = 128; off > 0; off >>= 1) {
            if (tid < off) { r2[tid] = fminf(r2[tid], r2[tid + off]); r3[tid] = fmaxf(r3[tid], r3[tid + off]); }
            __syncthreads();
        }
        if (tid == 0) {
            float* p = (bid < 4128) ? ws + PART_OFF + (size_t)(bid - 4096) * 2
                                    : ws + PART_OFF + 64 + (size_t)(bid - 4128) * 2;
            p[0] = r2[0]; p[1] = r3[0];
        }
    }
}

// ---------- K1: prep — weight quantize, BN affine + h1 range, rbn quantize ----------
__global__ __launch_bounds__(256) void k_prep(const float* __restrict__ conv1_w,
                                              const float* __restrict__ conv2_w,
                                              const float* __restrict__ bn1_w,
                                              const float* __restrict__ bn1_b,
                                              const float* __restrict__ rbn_w,
                                              const float* __restrict__ rbn_b,
                                              float* __restrict__ ws) {
    const int b = blockIdx.x, tid = threadIdx.x;
    __shared__ float ra[256], rb[256];
    __shared__ float s_mn, s_sc;

    if (b < 32) {                                  // conv1_w -> bf16 swizzled [ks][co][k64]
        ra[tid] = tid < 32 ? ws[PART_OFF + tid * 2] : INFINITY;
        rb[tid] = tid < 32 ? ws[PART_OFF + tid * 2 + 1] : -INFINITY;
        __syncthreads();
        for (int off = 128; off > 0; off >>= 1) {
            if (tid < off) { ra[tid] = fminf(ra[tid], ra[tid + off]); rb[tid] = fmaxf(rb[tid], rb[tid + off]); }
            __syncthreads();
        }
        if (tid == 0) { s_mn = ra[0]; s_sc = fmaxf((rb[0] - ra[0]) / 255.f, 1e-8f); }
        __syncthreads();
        const float mnw = s_mn, scw = s_sc;
        unsigned short* qw = (unsigned short*)(ws + QW1_OFF);
        const int base = b * 2048;
#pragma unroll
        for (int t = 0; t < 8; ++t) {
            const int i = base + t * 256 + tid;
            const int co = i >> 9, k = i & 511;
            const float v = conv1_w[i];
            const float qv = fmaf(rintf((v - mnw) / scw), scw, mnw);
            const int ks = k >> 6, kc = (k >> 3) & 7, klo = k & 7;
            qw[(((size_t)ks * 128 + co) << 6) + (((kc ^ (co & 7)) << 3) | klo)] = (unsigned short)f2bf(qv);
        }
    } else if (b < 40) {                           // conv2_w -> bf16 [co][k = tap*128 + ci]
        ra[tid] = tid < 8 ? ws[PART_OFF + 64 + tid * 2] : INFINITY;
        rb[tid] = tid < 8 ? ws[PART_OFF + 64 + tid * 2 + 1] : -INFINITY;
        __syncthreads();
        for (int off = 128; off > 0; off >>= 1) {
            if (tid < off) { ra[tid] = fminf(ra[tid], ra[tid + off]); rb[tid] = fmaxf(rb[tid], rb[tid + off]); }
            __syncthreads();
        }
        if (tid == 0) { s_mn = ra[0]; s_sc = fmaxf((rb[0] - ra[0]) / 255.f, 1e-8f); }
        __syncthreads();
        const float mnw = s_mn, scw = s_sc;
        unsigned short* qw2 = (unsigned short*)(ws + QW2_OFF);
        const int base = (b - 32) * 4608;
        for (int i2 = tid; i2 < 4608; i2 += 256) {
            const int i = base + i2;
            const int co = i / 1152, r = i % 1152, ci = r / 9, tap = r % 9;
            const float v = conv2_w[i];
            const float qv = fmaf(rintf((v - mnw) / scw), scw, mnw);
            qw2[(size_t)co * 1152 + tap * 128 + ci] = (unsigned short)f2bf(qv);
        }
    } else if (b == 40) {                          // BN affine + global h1 range
        float lmn = INFINITY, lmx = -INFINITY;
        for (int c = tid; c < 512; c += 256) {
            const float* p = ws + PSTAT_OFF + (size_t)c * 32;
            float s = 0.f, s2 = 0.f, cmn = INFINITY, cmx = -INFINITY;
            for (int g = 0; g < 8; ++g) {
                s += p[g * 4 + 0]; s2 += p[g * 4 + 1];
                cmn = fminf(cmn, p[g * 4 + 2]); cmx = fmaxf(cmx, p[g * 4 + 3]);
            }
            const float n = 50176.f;
            const float mean = s / n;
            const float var  = s2 / n - mean * mean;
            const float rstd = rsqrtf(var + 1e-5f);
            const float A  = rstd * bn1_w[c];
            const float Bc = bn1_b[c] - mean * A;
            ws[BNA_OFF + c] = A; ws[BNB_OFF + c] = Bc;
            const float v1 = A * cmn + Bc, v2 = A * cmx + Bc;
            lmn = fminf(lmn, fmaxf(0.f, fminf(v1, v2)));
            lmx = fmaxf(lmx, fmaxf(0.f, fmaxf(v1, v2)));
        }
        ra[tid] = lmn; rb[tid] = lmx;
        __syncthreads();
        for (int off = 128; off > 0; off >>= 1) {
            if (tid < off) { ra[tid] = fminf(ra[tid], ra[tid + off]); rb[tid] = fmaxf(rb[tid], rb[tid + off]); }
            __syncthreads();
        }
        if (tid == 0) {
            const float mn1 = ra[0], mx1 = rb[0];
            const float sc = fmaxf((mx1 - mn1) / 255.f, 1e-8f);
            ws[SCAL_OFF + 0] = mn1; ws[SCAL_OFF + 1] = sc; ws[SCAL_OFF + 2] = 1.f / sc; ws[SCAL_OFF + 6] = mx1;
        }
    } else {                                       // b == 41: rbn_w / rbn_b quantize
        for (int which = 0; which < 2; ++which) {
            const float* src = which ? rbn_b : rbn_w;
            const size_t dst = which ? QRB_OFF : QRW_OFF;
            float v = 0.f;
            ra[tid] = INFINITY; rb[tid] = -INFINITY;
            if (tid < 128) { v = src[tid]; ra[tid] = v; rb[tid] = v; }
            __syncthreads();
            for (int off = 128; off > 0; off >>= 1) {
                if (tid < off) { ra[tid] = fminf(ra[tid], ra[tid + off]); rb[tid] = fmaxf(rb[tid], rb[tid + off]); }
                __syncthreads();
            }
            if (tid == 0) { s_mn = ra[0]; s_sc = fmaxf((rb[0] - ra[0]) / 255.f, 1e-8f); }
            __syncthreads();
            if (tid < 128) ws[dst + tid] = fmaf(rintf((v - s_mn) / s_sc), s_sc, s_mn);
            __syncthreads();
        }
    }
}

// ---------- K2: 1x1 conv MFMA GEMM (M=128). A-frags direct from global (L2); ht-only LDS (14 KB);
//             4 blocks/CU; reg-prefetch staging; fused concat-copy + RBN partials; bf16 h2 ----------
__global__ __launch_bounds__(256, 4) void k_conv1(const float* __restrict__ x,
                                                  float* __restrict__ out,
                                                  float* __restrict__ ws) {
    __shared__ __align__(16) unsigned short ht[112 * 64];    // 14 KB
    const int tid = threadIdx.x;
    const int pt = blockIdx.x, b = blockIdx.y;
    const int p0 = pt * 112;
    const float mn1 = ws[SCAL_OFF + 0], sc1 = ws[SCAL_OFF + 1];
    const float inv1 = ws[SCAL_OFF + 2];
    const unsigned short* qw1 = (const unsigned short*)(ws + QW1_OFF);
    const float* xb = x + (size_t)b * C_IN * HW;
    float* outb = out + (size_t)b * C_TOT * HW;

    const int o = tid & 7, q = tid >> 3;
    const int wv = tid >> 6, g = (tid >> 4) & 3, r4 = tid & 15;

    // precomputed global A-frag pointers (byte-identical to previous wt staging)
    const unsigned short* afp[2][2];
#pragma unroll
    for (int ct = 0; ct < 2; ++ct)
#pragma unroll
        for (int ksub = 0; ksub < 2; ++ksub) {
            const int co = wv * 32 + ct * 16 + r4;
            const int kk = ksub * 4 + g;
            afp[ct][ksub] = qw1 + co * 64 + (((kk ^ (co & 7)) << 3));
        }

    f32x4 acc[2][7];
#pragma unroll
    for (int i = 0; i < 2; ++i)
#pragma unroll
        for (int j = 0; j < 7; ++j) acc[i][j] = f32x4{0.f, 0.f, 0.f, 0.f};

    f32x4 xreg[8];
    if (tid < 224) {
#pragma unroll
        for (int j = 0; j < 8; ++j)
            xreg[j] = *(const f32x4*)(xb + (size_t)(o * 8 + j) * HW + p0 + q * 4);
    }

    for (int ks = 0; ks < 8; ++ks) {
        if (tid < 224) {
            const int ci0 = ks * 64 + o * 8;
            float vv[8][4];
#pragma unroll
            for (int j = 0; j < 8; ++j) {
                const f32x4 v = xreg[j];
                __builtin_nontemporal_store(v, (f32x4*)(outb + (size_t)(ci0 + j) * HW + p0 + q * 4));
                const float A = ws[BNA_OFF + ci0 + j], Bc = ws[BNB_OFF + ci0 + j];
                vv[j][0] = fmaf(rintf((fmaxf(fmaf(v.x, A, Bc), 0.f) - mn1) * inv1), sc1, mn1);
                vv[j][1] = fmaf(rintf((fmaxf(fmaf(v.y, A, Bc), 0.f) - mn1) * inv1), sc1, mn1);
                vv[j][2] = fmaf(rintf((fmaxf(fmaf(v.z, A, Bc), 0.f) - mn1) * inv1), sc1, mn1);
                vv[j][3] = fmaf(rintf((fmaxf(fmaf(v.w, A, Bc), 0.f) - mn1) * inv1), sc1, mn1);
            }
            if (ks < 7) {
                const int ci0n = (ks + 1) * 64 + o * 8;
#pragma unroll
                for (int j = 0; j < 8; ++j)
                    xreg[j] = *(const f32x4*)(xb + (size_t)(ci0n + j) * HW + p0 + q * 4);
            }
#pragma unroll
            for (int r = 0; r < 4; ++r) {
                const int p = q * 4 + r;
                uint4 pk;
                pk.x = f2bf(vv[0][r]) | (f2bf(vv[1][r]) << 16);
                pk.y = f2bf(vv[2][r]) | (f2bf(vv[3][r]) << 16);
                pk.z = f2bf(vv[4][r]) | (f2bf(vv[5][r]) << 16);
                pk.w = f2bf(vv[6][r]) | (f2bf(vv[7][r]) << 16);
                *(uint4*)&ht[p * 64 + ((o ^ (p & 7)) << 3)] = pk;
            }
        }
        __syncthreads();

        const size_t ksoff = (size_t)ks * 8192;
#pragma unroll
        for (int ksub = 0; ksub < 2; ++ksub) {
            const int kk = ksub * 4 + g;
            bf16x8 af[2], bfr[7];
#pragma unroll
            for (int ct = 0; ct < 2; ++ct)
                af[ct] = *(const bf16x8*)(afp[ct][ksub] + ksoff);   // L2-hot global
#pragma unroll
            for (int pf = 0; pf < 7; ++pf) {
                const int p = pf * 16 + r4;
                bfr[pf] = *(const bf16x8*)&ht[p * 64 + ((kk ^ (p & 7)) << 3)];
            }
#pragma unroll
            for (int ct = 0; ct < 2; ++ct)
#pragma unroll
                for (int pf = 0; pf < 7; ++pf)
                    acc[ct][pf] = __builtin_amdgcn_mfma_f32_16x16x32_bf16(af[ct], bfr[pf], acc[ct][pf], 0, 0, 0);
        }
        __syncthreads();
    }

    unsigned short* hb = (unsigned short*)(ws + H2_OFF) + (size_t)b * C_MID * HW;
#pragma unroll
    for (int ct = 0; ct < 2; ++ct) {
        const int co0 = wv * 32 + ct * 16 + g * 4;
#pragma unroll
        for (int pf = 0; pf < 7; ++pf) {
            const int p = p0 + pf * 16 + r4;
#pragma unroll
            for (int r = 0; r < 4; ++r)
                hb[(size_t)(co0 + r) * HW + p] = (unsigned short)f2bf(acc[ct][pf][r]);
        }
    }

#pragma unroll
    for (int ct = 0; ct < 2; ++ct)
#pragma unroll
        for (int r = 0; r < 4; ++r) {
            float s = 0.f, mn = INFINITY, mx = -INFINITY;
#pragma unroll
            for (int pf = 0; pf < 7; ++pf) {
                const float v = acc[ct][pf][r];
                s += v; mn = fminf(mn, v); mx = fmaxf(mx, v);
            }
#pragma unroll
            for (int m = 1; m < 16; m <<= 1) {
                s  += __shfl_xor(s, m, 64);
                mn  = fminf(mn, __shfl_xor(mn, m, 64));
                mx  = fmaxf(mx, __shfl_xor(mx, m, 64));
            }
            if (r4 == 0) {
                const int co = wv * 32 + ct * 16 + g * 4 + r;
                float* dst = ws + RP_OFF + (((size_t)co * 64 + b) * 7 + pt) * 3;
                dst[0] = s; dst[1] = mn; dst[2] = mx;
            }
        }
}

// ---------- K3: combine RBN partials -> per-channel affine + h3 endpoints (PART2) ----------
__global__ __launch_bounds__(64) void k_rbn_combine(float* __restrict__ ws) {
    const int c = blockIdx.x, t = threadIdx.x;
    const int ch = t >> 2, sub = t & 3;
    const int b = ch * 4 + sub;
    const float* rp = ws + RP_OFF + ((size_t)c * 64 + b) * 21;
    float s = 0.f, mn = INFINITY, mx = -INFINITY;
#pragma unroll
    for (int pt = 0; pt < 7; ++pt) {
        s += rp[pt * 3 + 0];
        mn = fminf(mn, rp[pt * 3 + 1]);
        mx = fmaxf(mx, rp[pt * 3 + 2]);
    }
#pragma unroll
    for (int m = 1; m < 4; m <<= 1) {
        s  += __shfl_xor(s, m, 64);
        mn  = fminf(mn, __shfl_xor(mn, m, 64));
        mx  = fmaxf(mx, __shfl_xor(mx, m, 64));
    }
    float smx = mx, smn = mn, stot = s, gmn = mn, gmx = mx;
#pragma unroll
    for (int m = 4; m < 64; m <<= 1) {
        smx  += __shfl_xor(smx, m, 64);
        smn  += __shfl_xor(smn, m, 64);
        stot += __shfl_xor(stot, m, 64);
        gmn   = fminf(gmn, __shfl_xor(gmn, m, 64));
        gmx   = fmaxf(gmx, __shfl_xor(gmx, m, 64));
    }
    if (t == 0) {
        const float mm = smx * (1.f / 16.f), mnm = smn * (1.f / 16.f);
        const float mean = stot / 50176.f;
        const double PI_D = 3.14159265358979323846;
        const double sfd = 0.175 * (1.0 + sqrt(PI_D * log(4.0))) / sqrt(2.0 * log(3136.0));
        const float scale = 1.f / ((mm - mnm) * (float)sfd + 1e-5f);
        const float A  = scale * ws[QRW_OFF + c];
        const float Bc = ws[QRB_OFF + c] - mean * A;
        ws[A2_OFF + c] = A; ws[B2_OFF + c] = Bc;
        const float v1 = A * gmn + Bc, v2 = A * gmx + Bc;
        ws[PART2_OFF + c * 2 + 0] = fmaxf(0.f, fminf(v1, v2));
        ws[PART2_OFF + c * 2 + 1] = fmaxf(0.f, fmaxf(v1, v2));
    }
}

// ---------- K4: 3x3 conv via MFMA implicit im2col, 256 threads, h2 bf16, h3 range from PART2 ----------
__global__ __launch_bounds__(256, 2) void k_conv2(float* __restrict__ out, const float* __restrict__ ws) {
    __shared__ __align__(16) unsigned short lact[7 * 30 * 128];   // 52.5 KB
    __shared__ float sra[128], srb[128];
    __shared__ float s_mn3, s_mx3, s_sc3, s_inv3;
    const int tid = threadIdx.x;
    const int pt = blockIdx.x, b = blockIdx.y;
    const int y0 = pt * 4;

    if (tid < 128) { sra[tid] = ws[PART2_OFF + tid * 2]; srb[tid] = ws[PART2_OFF + tid * 2 + 1]; }
    __syncthreads();
    for (int off = 64; off > 0; off >>= 1) {
        if (tid < off) { sra[tid] = fminf(sra[tid], sra[tid + off]); srb[tid] = fmaxf(srb[tid], srb[tid + off]); }
        __syncthreads();
    }
    if (tid == 0) {
        const float mn3 = sra[0], mx3 = srb[0];
        const float sc = fmaxf((mx3 - mn3) / 255.f, 1e-8f);
        s_mn3 = mn3; s_mx3 = mx3; s_sc3 = sc; s_inv3 = 1.f / sc;
    }
    {
        const uint4 z = {0u, 0u, 0u, 0u};
        uint4* lp = (uint4*)lact;
        for (int i = tid; i < 3360; i += 256) lp[i] = z;
    }
    __syncthreads();
    const float mn3 = s_mn3, mx3 = s_mx3, sc3 = s_sc3, inv3 = s_inv3;

    const unsigned short* h2b = (const unsigned short*)(ws + H2_OFF) + (size_t)b * C_MID * HW;
    for (int task = tid; task < 672; task += 256) {
        const int oct = task / 42, rem = task % 42, r = rem / 7, xq = rem % 7;
        const int gy = y0 - 1 + r;
        if (gy < 0 || gy > 27) continue;
        float vv[8][4];
#pragma unroll
        for (int j = 0; j < 8; ++j) {
            const int ci = oct * 8 + j;
            const ushort4 v = *(const ushort4*)(h2b + (size_t)ci * HW + gy * 28 + xq * 4);
            const float A = ws[A2_OFF + ci], Bc = ws[B2_OFF + ci];
            vv[j][0] = qact(fmaxf(0.f, fmaf(bf2f(v.x), A, Bc)), mn3, mx3, inv3, sc3);
            vv[j][1] = qact(fmaxf(0.f, fmaf(bf2f(v.y), A, Bc)), mn3, mx3, inv3, sc3);
            vv[j][2] = qact(fmaxf(0.f, fmaf(bf2f(v.z), A, Bc)), mn3, mx3, inv3, sc3);
            vv[j][3] = qact(fmaxf(0.f, fmaf(bf2f(v.w), A, Bc)), mn3, mx3, inv3, sc3);
        }
#pragma unroll
        for (int xi = 0; xi < 4; ++xi) {
            const int col = xq * 4 + xi + 1;
            const int phys = (oct + col) & 15;
            uint4 pk;
            pk.x = f2bf(vv[0][xi]) | (f2bf(vv[1][xi]) << 16);
            pk.y = f2bf(vv[2][xi]) | (f2bf(vv[3][xi]) << 16);
            pk.z = f2bf(vv[4][xi]) | (f2bf(vv[5][xi]) << 16);
            pk.w = f2bf(vv[6][xi]) | (f2bf(vv[7][xi]) << 16);
            *(uint4*)&lact[((r * 30 + col) * 16 + phys) * 8] = pk;
        }
    }
    __syncthreads();

    const int wv = tid >> 6, lane = tid & 63, r4 = lane & 15, g = lane >> 4;
    int py[2], px[2];
#pragma unroll
    for (int i = 0; i < 2; ++i) {
        const int p = (wv * 2 + i) * 16 + r4;
        py[i] = p / 28; px[i] = p % 28;
    }
    f32x4 acc[2][2];
#pragma unroll
    for (int ct = 0; ct < 2; ++ct)
#pragma unroll
        for (int i = 0; i < 2; ++i) acc[ct][i] = f32x4{0.f, 0.f, 0.f, 0.f};

    const unsigned short* qw2 = (const unsigned short*)(ws + QW2_OFF);
    for (int tap = 0; tap < 9; ++tap) {
        const int dy = tap / 3, dx = tap % 3;
        bf16x8 afr[2][4];
#pragma unroll
        for (int ct = 0; ct < 2; ++ct)
#pragma unroll
            for (int c4 = 0; c4 < 4; ++c4) {
                const int co = ct * 16 + r4;
                afr[ct][c4] = *(const bf16x8*)&qw2[(size_t)co * 1152 + tap * 128 + c4 * 32 + g * 8];
            }
#pragma unroll
        for (int c4 = 0; c4 < 4; ++c4) {
            bf16x8 bfr[2];
#pragma unroll
            for (int i = 0; i < 2; ++i) {
                const int row = py[i] + dy, col = px[i] + dx;
                const int phys = (c4 * 4 + g + col) & 15;
                bfr[i] = *(const bf16x8*)&lact[((row * 30 + col) * 16 + phys) * 8];
            }
#pragma unroll
            for (int ct = 0; ct < 2; ++ct)
#pragma unroll
                for (int i = 0; i < 2; ++i)
                    acc[ct][i] = __builtin_amdgcn_mfma_f32_16x16x32_bf16(afr[ct][c4], bfr[i], acc[ct][i], 0, 0, 0);
        }
    }

#pragma unroll
    for (int ct = 0; ct < 2; ++ct)
#pragma unroll
        for (int i = 0; i < 2; ++i) {
            const int pf = wv * 2 + i;
            if (pf < 7) {
                const int p = pf * 16 + r4;
#pragma unroll
                for (int r = 0; r < 4; ++r) {
                    const int co = ct * 16 + g * 4 + r;
                    out[((size_t)b * C_TOT + 512 + co) * HW + y0 * 28 + p] = acc[ct][i][r];
                }
            }
        }
}

extern "C" void kernel_launch(void* const* d_in, const int* in_sizes, int n_in,
                              void* d_out, int out_size, void* d_ws, size_t ws_size,
                              hipStream_t stream) {
    const float* x       = (const float*)d_in[0];
    const float* bn1_w   = (const float*)d_in[1];
    const float* bn1_b   = (const float*)d_in[2];
    const float* conv1_w = (const float*)d_in[3];
    const float* rbn_w   = (const float*)d_in[4];
    const float* rbn_b   = (const float*)d_in[5];
    const float* conv2_w = (const float*)d_in[6];
    float* out = (float*)d_out;
    float* ws  = (float*)d_ws;   // needs ~27 MB

    k_stats<<<4136, 256, 0, stream>>>(x, conv1_w, conv2_w, ws);
    k_prep<<<42, 256, 0, stream>>>(conv1_w, conv2_w, bn1_w, bn1_b, rbn_w, rbn_b, ws);
    k_conv1<<<dim3(7, 64), 256, 0, stream>>>(x, out, ws);
    k_rbn_combine<<<128, 64, 0, stream>>>(ws);
    k_conv2<<<dim3(7, 64), 256, 0, stream>>>(out, ws);
}

// Round 12
// 118.670 us; speedup vs baseline: 1.0359x; 1.0359x over previous
//
#include <hip/hip_runtime.h>
#include <math.h>

// Dims: x[64,512,28,28] -> out[64,544,28,28] fp32
static constexpr int BB    = 64;
static constexpr int C_IN  = 512;
static constexpr int C_MID = 128;
static constexpr int C_OUT = 32;
static constexpr int C_TOT = 544;
static constexpr int HW    = 784;   // 28*28

// ---- workspace layout (float offsets). ~27 MB ----
static constexpr size_t H2_OFF    = 0;                         // bf16 h2: 64*128*784 ushorts
static constexpr size_t QW1_OFF   = 6422528;                   // bf16 [8][128][64] swizzled
static constexpr size_t QW2_OFF   = QW1_OFF + 65536;           // bf16 [co32][k1152]
static constexpr size_t PSTAT_OFF = QW2_OFF + 49152;           // [512][8][4] {s,s2,mn,mx}
static constexpr size_t BNA_OFF   = PSTAT_OFF + 16384;         // 512
static constexpr size_t BNB_OFF   = BNA_OFF + 512;             // 512
static constexpr size_t A2_OFF    = BNB_OFF + 512;             // 128
static constexpr size_t B2_OFF    = A2_OFF + 128;
static constexpr size_t QRW_OFF   = B2_OFF + 128;
static constexpr size_t QRB_OFF   = QRW_OFF + 128;
static constexpr size_t SCAL_OFF  = QRB_OFF + 128;             // 16: 0=mn1 1=sc1 2=inv1 6=mx1
static constexpr size_t PART_OFF  = SCAL_OFF + 16;             // weight partials: w1[32][2], w2 at +64 [8][2]
static constexpr size_t RP_OFF    = PART_OFF + 128;            // rbn partials [co128][b64][pt7][3]
static constexpr size_t PART2_OFF = RP_OFF + 172032;           // per-channel h3 lo/hi [128][2]

// k_stats block ranges
static constexpr int NCOPY = 1792;                  // 64 images x 28 chunks (3584 f4 each)
static constexpr int NSTAT = 4096;                  // 512 ch x 8 image-groups

#define DEVFN __device__ __forceinline__

typedef __bf16 bf16x8 __attribute__((ext_vector_type(8)));
typedef float  f32x4  __attribute__((ext_vector_type(4)));

DEVFN float qact(float v, float mn, float mx, float inv, float sc) {
    v = fminf(fmaxf(v, mn), mx);
    return fmaf(rintf((v - mn) * inv), sc, mn);   // rintf == round-half-even == jnp.round
}

DEVFN unsigned f2bf(float f) {                    // fp32 -> bf16 bits, RNE
    unsigned u = __float_as_uint(f);
    return (u + 0x7fffu + ((u >> 16) & 1u)) >> 16;
}

DEVFN float bf2f(unsigned short h) { return __uint_as_float((unsigned)h << 16); }

// ---------- K0: sequential concat-copy (1792) + per-channel x stats (4096) + weight partials (40) ----------
__global__ __launch_bounds__(256) void k_stats(const float* __restrict__ x,
                                               const float* __restrict__ conv1_w,
                                               const float* __restrict__ conv2_w,
                                               float* __restrict__ out,
                                               float* __restrict__ ws) {
    const int bid = blockIdx.x, tid = threadIdx.x;

    if (bid < NCOPY) {                             // copy: contiguous 3584-f4 span, NT store
        const int b = bid / 28, blk = bid % 28;
        const f32x4* src = (const f32x4*)(x + (size_t)b * C_IN * HW) + (size_t)blk * 3584;
        f32x4* dst = (f32x4*)(out + (size_t)b * C_TOT * HW) + (size_t)blk * 3584;
#pragma unroll
        for (int i = 0; i < 14; ++i)
            __builtin_nontemporal_store(src[i * 256 + tid], dst + i * 256 + tid);
        return;
    }

    __shared__ float r0[256], r1[256], r2[256], r3[256];
    if (bid < NCOPY + NSTAT) {                     // x stats: (c, 8-image group), channel-major
        const int sb = bid - NCOPY;
        const int c = sb >> 3, bg = sb & 7;
        float s = 0.f, s2 = 0.f, mn = INFINITY, mx = -INFINITY;
        for (int i = tid; i < 1568; i += 256) {
            const int b = bg * 8 + i / 196, j = i % 196;
            const float4 v = ((const float4*)(x + ((size_t)b * C_IN + c) * HW))[j];
            s  += (v.x + v.y) + (v.z + v.w);
            s2 += v.x * v.x + v.y * v.y + v.z * v.z + v.w * v.w;
            mn = fminf(mn, fminf(fminf(v.x, v.y), fminf(v.z, v.w)));
            mx = fmaxf(mx, fmaxf(fmaxf(v.x, v.y), fmaxf(v.z, v.w)));
        }
        r0[tid] = s; r1[tid] = s2; r2[tid] = mn; r3[tid] = mx;
        __syncthreads();
        for (int off = 128; off > 0; off >>= 1) {
            if (tid < off) {
                r0[tid] += r0[tid + off];
                r1[tid] += r1[tid + off];
                r2[tid] = fminf(r2[tid], r2[tid + off]);
                r3[tid] = fmaxf(r3[tid], r3[tid + off]);
            }
            __syncthreads();
        }
        if (tid == 0) {
            float* p = ws + PSTAT_OFF + ((size_t)c * 8 + bg) * 4;
            p[0] = r0[0]; p[1] = r1[0]; p[2] = r2[0]; p[3] = r3[0];
        }
    } else {                                       // weight min/max -> fixed partial slots
        const int wb = bid - NCOPY - NSTAT;        // 0..39
        float mn = INFINITY, mx = -INFINITY;
        if (wb < 32) {
            const float4* src = (const float4*)conv1_w + (size_t)wb * 512;
            for (int i = tid; i < 512; i += 256) {
                const float4 v = src[i];
                mn = fminf(mn, fminf(fminf(v.x, v.y), fminf(v.z, v.w)));
                mx = fmaxf(mx, fmaxf(fmaxf(v.x, v.y), fmaxf(v.z, v.w)));
            }
        } else {
            const float4* src = (const float4*)conv2_w + (size_t)(wb - 32) * 1152;
            for (int i = tid; i < 1152; i += 256) {
                const float4 v = src[i];
                mn = fminf(mn, fminf(fminf(v.x, v.y), fminf(v.z, v.w)));
                mx = fmaxf(mx, fmaxf(fmaxf(v.x, v.y), fmaxf(v.z, v.w)));
            }
        }
        r2[tid] = mn; r3[tid] = mx;
        __syncthreads();
        for (int off = 128; off > 0; off >>= 1) {
            if (tid < off) { r2[tid] = fminf(r2[tid], r2[tid + off]); r3[tid] = fmaxf(r3[tid], r3[tid + off]); }
            __syncthreads();
        }
        if (tid == 0) {
            float* p = (wb < 32) ? ws + PART_OFF + (size_t)wb * 2
                                 : ws + PART_OFF + 64 + (size_t)(wb - 32) * 2;
            p[0] = r2[0]; p[1] = r3[0];
        }
    }
}

// ---------- K1: prep — weight quantize, BN affine + h1 range, rbn quantize ----------
__global__ __launch_bounds__(256) void k_prep(const float* __restrict__ conv1_w,
                                              const float* __restrict__ conv2_w,
                                              const float* __restrict__ bn1_w,
                                              const float* __restrict__ bn1_b,
                                              const float* __restrict__ rbn_w,
                                              const float* __restrict__ rbn_b,
                                              float* __restrict__ ws) {
    const int b = blockIdx.x, tid = threadIdx.x;
    __shared__ float ra[256], rb[256];
    __shared__ float s_mn, s_sc;

    if (b < 32) {                                  // conv1_w -> bf16 swizzled [ks][co][k64]
        ra[tid] = tid < 32 ? ws[PART_OFF + tid * 2] : INFINITY;
        rb[tid] = tid < 32 ? ws[PART_OFF + tid * 2 + 1] : -INFINITY;
        __syncthreads();
        for (int off = 128; off > 0; off >>= 1) {
            if (tid < off) { ra[tid] = fminf(ra[tid], ra[tid + off]); rb[tid] = fmaxf(rb[tid], rb[tid + off]); }
            __syncthreads();
        }
        if (tid == 0) { s_mn = ra[0]; s_sc = fmaxf((rb[0] - ra[0]) / 255.f, 1e-8f); }
        __syncthreads();
        const float mnw = s_mn, scw = s_sc;
        unsigned short* qw = (unsigned short*)(ws + QW1_OFF);
        const int base = b * 2048;
#pragma unroll
        for (int t = 0; t < 8; ++t) {
            const int i = base + t * 256 + tid;
            const int co = i >> 9, k = i & 511;
            const float v = conv1_w[i];
            const float qv = fmaf(rintf((v - mnw) / scw), scw, mnw);
            const int ks = k >> 6, kc = (k >> 3) & 7, klo = k & 7;
            qw[(((size_t)ks * 128 + co) << 6) + (((kc ^ (co & 7)) << 3) | klo)] = (unsigned short)f2bf(qv);
        }
    } else if (b < 40) {                           // conv2_w -> bf16 [co][k = tap*128 + ci]
        ra[tid] = tid < 8 ? ws[PART_OFF + 64 + tid * 2] : INFINITY;
        rb[tid] = tid < 8 ? ws[PART_OFF + 64 + tid * 2 + 1] : -INFINITY;
        __syncthreads();
        for (int off = 128; off > 0; off >>= 1) {
            if (tid < off) { ra[tid] = fminf(ra[tid], ra[tid + off]); rb[tid] = fmaxf(rb[tid], rb[tid + off]); }
            __syncthreads();
        }
        if (tid == 0) { s_mn = ra[0]; s_sc = fmaxf((rb[0] - ra[0]) / 255.f, 1e-8f); }
        __syncthreads();
        const float mnw = s_mn, scw = s_sc;
        unsigned short* qw2 = (unsigned short*)(ws + QW2_OFF);
        const int base = (b - 32) * 4608;
        for (int i2 = tid; i2 < 4608; i2 += 256) {
            const int i = base + i2;
            const int co = i / 1152, r = i % 1152, ci = r / 9, tap = r % 9;
            const float v = conv2_w[i];
            const float qv = fmaf(rintf((v - mnw) / scw), scw, mnw);
            qw2[(size_t)co * 1152 + tap * 128 + ci] = (unsigned short)f2bf(qv);
        }
    } else if (b == 40) {                          // BN affine + global h1 range
        float lmn = INFINITY, lmx = -INFINITY;
        for (int c = tid; c < 512; c += 256) {
            const float* p = ws + PSTAT_OFF + (size_t)c * 32;
            float s = 0.f, s2 = 0.f, cmn = INFINITY, cmx = -INFINITY;
            for (int g = 0; g < 8; ++g) {
                s += p[g * 4 + 0]; s2 += p[g * 4 + 1];
                cmn = fminf(cmn, p[g * 4 + 2]); cmx = fmaxf(cmx, p[g * 4 + 3]);
            }
            const float n = 50176.f;
            const float mean = s / n;
            const float var  = s2 / n - mean * mean;
            const float rstd = rsqrtf(var + 1e-5f);
            const float A  = rstd * bn1_w[c];
            const float Bc = bn1_b[c] - mean * A;
            ws[BNA_OFF + c] = A; ws[BNB_OFF + c] = Bc;
            const float v1 = A * cmn + Bc, v2 = A * cmx + Bc;
            lmn = fminf(lmn, fmaxf(0.f, fminf(v1, v2)));
            lmx = fmaxf(lmx, fmaxf(0.f, fmaxf(v1, v2)));
        }
        ra[tid] = lmn; rb[tid] = lmx;
        __syncthreads();
        for (int off = 128; off > 0; off >>= 1) {
            if (tid < off) { ra[tid] = fminf(ra[tid], ra[tid + off]); rb[tid] = fmaxf(rb[tid], rb[tid + off]); }
            __syncthreads();
        }
        if (tid == 0) {
            const float mn1 = ra[0], mx1 = rb[0];
            const float sc = fmaxf((mx1 - mn1) / 255.f, 1e-8f);
            ws[SCAL_OFF + 0] = mn1; ws[SCAL_OFF + 1] = sc; ws[SCAL_OFF + 2] = 1.f / sc; ws[SCAL_OFF + 6] = mx1;
        }
    } else {                                       // b == 41: rbn_w / rbn_b quantize
        for (int which = 0; which < 2; ++which) {
            const float* src = which ? rbn_b : rbn_w;
            const size_t dst = which ? QRB_OFF : QRW_OFF;
            float v = 0.f;
            ra[tid] = INFINITY; rb[tid] = -INFINITY;
            if (tid < 128) { v = src[tid]; ra[tid] = v; rb[tid] = v; }
            __syncthreads();
            for (int off = 128; off > 0; off >>= 1) {
                if (tid < off) { ra[tid] = fminf(ra[tid], ra[tid + off]); rb[tid] = fmaxf(rb[tid], rb[tid + off]); }
                __syncthreads();
            }
            if (tid == 0) { s_mn = ra[0]; s_sc = fmaxf((rb[0] - ra[0]) / 255.f, 1e-8f); }
            __syncthreads();
            if (tid < 128) ws[dst + tid] = fmaf(rintf((v - s_mn) / s_sc), s_sc, s_mn);
            __syncthreads();
        }
    }
}

// ---------- K2: 1x1 conv MFMA GEMM (M=128), lean: x L3-read + bf16 h2 write + RBN partials ----------
__global__ __launch_bounds__(256, 2) void k_conv1(const float* __restrict__ x,
                                                  float* __restrict__ ws) {
    __shared__ __align__(16) unsigned short wt[128 * 64];    // 16 KB
    __shared__ __align__(16) unsigned short ht[112 * 64];    // 14 KB
    const int tid = threadIdx.x;
    const int pt = blockIdx.x, b = blockIdx.y;
    const int p0 = pt * 112;
    const float mn1 = ws[SCAL_OFF + 0], sc1 = ws[SCAL_OFF + 1];
    const float inv1 = ws[SCAL_OFF + 2];
    const unsigned short* qw1 = (const unsigned short*)(ws + QW1_OFF);
    const float* xb = x + (size_t)b * C_IN * HW;

    const int o = tid & 7, q = tid >> 3;
    const int wv = tid >> 6, g = (tid >> 4) & 3, r4 = tid & 15;

    f32x4 acc[2][7];
#pragma unroll
    for (int i = 0; i < 2; ++i)
#pragma unroll
        for (int j = 0; j < 7; ++j) acc[i][j] = f32x4{0.f, 0.f, 0.f, 0.f};

    f32x4 xreg[8];
    if (tid < 224) {
#pragma unroll
        for (int j = 0; j < 8; ++j)
            xreg[j] = *(const f32x4*)(xb + (size_t)(o * 8 + j) * HW + p0 + q * 4);
    }

    for (int ks = 0; ks < 8; ++ks) {
        const float4* wsrc = (const float4*)(qw1 + (size_t)ks * 8192);
        float4* wdst = (float4*)wt;
#pragma unroll
        for (int i = 0; i < 4; ++i) wdst[tid + i * 256] = wsrc[tid + i * 256];

        if (tid < 224) {
            const int ci0 = ks * 64 + o * 8;
            float vv[8][4];
#pragma unroll
            for (int j = 0; j < 8; ++j) {
                const f32x4 v = xreg[j];
                const float A = ws[BNA_OFF + ci0 + j], Bc = ws[BNB_OFF + ci0 + j];
                vv[j][0] = fmaf(rintf((fmaxf(fmaf(v.x, A, Bc), 0.f) - mn1) * inv1), sc1, mn1);
                vv[j][1] = fmaf(rintf((fmaxf(fmaf(v.y, A, Bc), 0.f) - mn1) * inv1), sc1, mn1);
                vv[j][2] = fmaf(rintf((fmaxf(fmaf(v.z, A, Bc), 0.f) - mn1) * inv1), sc1, mn1);
                vv[j][3] = fmaf(rintf((fmaxf(fmaf(v.w, A, Bc), 0.f) - mn1) * inv1), sc1, mn1);
            }
            if (ks < 7) {
                const int ci0n = (ks + 1) * 64 + o * 8;
#pragma unroll
                for (int j = 0; j < 8; ++j)
                    xreg[j] = *(const f32x4*)(xb + (size_t)(ci0n + j) * HW + p0 + q * 4);
            }
#pragma unroll
            for (int r = 0; r < 4; ++r) {
                const int p = q * 4 + r;
                uint4 pk;
                pk.x = f2bf(vv[0][r]) | (f2bf(vv[1][r]) << 16);
                pk.y = f2bf(vv[2][r]) | (f2bf(vv[3][r]) << 16);
                pk.z = f2bf(vv[4][r]) | (f2bf(vv[5][r]) << 16);
                pk.w = f2bf(vv[6][r]) | (f2bf(vv[7][r]) << 16);
                *(uint4*)&ht[p * 64 + ((o ^ (p & 7)) << 3)] = pk;
            }
        }
        __syncthreads();

#pragma unroll
        for (int ksub = 0; ksub < 2; ++ksub) {
            const int kk = ksub * 4 + g;
            bf16x8 af[2], bfr[7];
#pragma unroll
            for (int ct = 0; ct < 2; ++ct) {
                const int co = wv * 32 + ct * 16 + r4;
                af[ct] = *(const bf16x8*)&wt[co * 64 + ((kk ^ (co & 7)) << 3)];
            }
#pragma unroll
            for (int pf = 0; pf < 7; ++pf) {
                const int p = pf * 16 + r4;
                bfr[pf] = *(const bf16x8*)&ht[p * 64 + ((kk ^ (p & 7)) << 3)];
            }
#pragma unroll
            for (int ct = 0; ct < 2; ++ct)
#pragma unroll
                for (int pf = 0; pf < 7; ++pf)
                    acc[ct][pf] = __builtin_amdgcn_mfma_f32_16x16x32_bf16(af[ct], bfr[pf], acc[ct][pf], 0, 0, 0);
        }
        __syncthreads();
    }

    unsigned short* hb = (unsigned short*)(ws + H2_OFF) + (size_t)b * C_MID * HW;
#pragma unroll
    for (int ct = 0; ct < 2; ++ct) {
        const int co0 = wv * 32 + ct * 16 + g * 4;
#pragma unroll
        for (int pf = 0; pf < 7; ++pf) {
            const int p = p0 + pf * 16 + r4;
#pragma unroll
            for (int r = 0; r < 4; ++r)
                hb[(size_t)(co0 + r) * HW + p] = (unsigned short)f2bf(acc[ct][pf][r]);
        }
    }

#pragma unroll
    for (int ct = 0; ct < 2; ++ct)
#pragma unroll
        for (int r = 0; r < 4; ++r) {
            float s = 0.f, mn = INFINITY, mx = -INFINITY;
#pragma unroll
            for (int pf = 0; pf < 7; ++pf) {
                const float v = acc[ct][pf][r];
                s += v; mn = fminf(mn, v); mx = fmaxf(mx, v);
            }
#pragma unroll
            for (int m = 1; m < 16; m <<= 1) {
                s  += __shfl_xor(s, m, 64);
                mn  = fminf(mn, __shfl_xor(mn, m, 64));
                mx  = fmaxf(mx, __shfl_xor(mx, m, 64));
            }
            if (r4 == 0) {
                const int co = wv * 32 + ct * 16 + g * 4 + r;
                float* dst = ws + RP_OFF + (((size_t)co * 64 + b) * 7 + pt) * 3;
                dst[0] = s; dst[1] = mn; dst[2] = mx;
            }
        }
}

// ---------- K3: combine RBN partials -> per-channel affine + h3 endpoints (PART2) ----------
__global__ __launch_bounds__(64) void k_rbn_combine(float* __restrict__ ws) {
    const int c = blockIdx.x, t = threadIdx.x;
    const int ch = t >> 2, sub = t & 3;
    const int b = ch * 4 + sub;
    const float* rp = ws + RP_OFF + ((size_t)c * 64 + b) * 21;
    float s = 0.f, mn = INFINITY, mx = -INFINITY;
#pragma unroll
    for (int pt = 0; pt < 7; ++pt) {
        s += rp[pt * 3 + 0];
        mn = fminf(mn, rp[pt * 3 + 1]);
        mx = fmaxf(mx, rp[pt * 3 + 2]);
    }
#pragma unroll
    for (int m = 1; m < 4; m <<= 1) {
        s  += __shfl_xor(s, m, 64);
        mn  = fminf(mn, __shfl_xor(mn, m, 64));
        mx  = fmaxf(mx, __shfl_xor(mx, m, 64));
    }
    float smx = mx, smn = mn, stot = s, gmn = mn, gmx = mx;
#pragma unroll
    for (int m = 4; m < 64; m <<= 1) {
        smx  += __shfl_xor(smx, m, 64);
        smn  += __shfl_xor(smn, m, 64);
        stot += __shfl_xor(stot, m, 64);
        gmn   = fminf(gmn, __shfl_xor(gmn, m, 64));
        gmx   = fmaxf(gmx, __shfl_xor(gmx, m, 64));
    }
    if (t == 0) {
        const float mm = smx * (1.f / 16.f), mnm = smn * (1.f / 16.f);
        const float mean = stot / 50176.f;
        const double PI_D = 3.14159265358979323846;
        const double sfd = 0.175 * (1.0 + sqrt(PI_D * log(4.0))) / sqrt(2.0 * log(3136.0));
        const float scale = 1.f / ((mm - mnm) * (float)sfd + 1e-5f);
        const float A  = scale * ws[QRW_OFF + c];
        const float Bc = ws[QRB_OFF + c] - mean * A;
        ws[A2_OFF + c] = A; ws[B2_OFF + c] = Bc;
        const float v1 = A * gmn + Bc, v2 = A * gmx + Bc;
        ws[PART2_OFF + c * 2 + 0] = fmaxf(0.f, fminf(v1, v2));
        ws[PART2_OFF + c * 2 + 1] = fmaxf(0.f, fmaxf(v1, v2));
    }
}

// ---------- K4: 3x3 conv via MFMA implicit im2col, 256 threads, h2 bf16, h3 range from PART2 ----------
__global__ __launch_bounds__(256, 2) void k_conv2(float* __restrict__ out, const float* __restrict__ ws) {
    __shared__ __align__(16) unsigned short lact[7 * 30 * 128];   // 52.5 KB
    __shared__ float sra[128], srb[128];
    __shared__ float s_mn3, s_mx3, s_sc3, s_inv3;
    const int tid = threadIdx.x;
    const int pt = blockIdx.x, b = blockIdx.y;
    const int y0 = pt * 4;

    if (tid < 128) { sra[tid] = ws[PART2_OFF + tid * 2]; srb[tid] = ws[PART2_OFF + tid * 2 + 1]; }
    __syncthreads();
    for (int off = 64; off > 0; off >>= 1) {
        if (tid < off) { sra[tid] = fminf(sra[tid], sra[tid + off]); srb[tid] = fmaxf(srb[tid], srb[tid + off]); }
        __syncthreads();
    }
    if (tid == 0) {
        const float mn3 = sra[0], mx3 = srb[0];
        const float sc = fmaxf((mx3 - mn3) / 255.f, 1e-8f);
        s_mn3 = mn3; s_mx3 = mx3; s_sc3 = sc; s_inv3 = 1.f / sc;
    }
    {
        const uint4 z = {0u, 0u, 0u, 0u};
        uint4* lp = (uint4*)lact;
        for (int i = tid; i < 3360; i += 256) lp[i] = z;
    }
    __syncthreads();
    const float mn3 = s_mn3, mx3 = s_mx3, sc3 = s_sc3, inv3 = s_inv3;

    const unsigned short* h2b = (const unsigned short*)(ws + H2_OFF) + (size_t)b * C_MID * HW;
    for (int task = tid; task < 672; task += 256) {
        const int oct = task / 42, rem = task % 42, r = rem / 7, xq = rem % 7;
        const int gy = y0 - 1 + r;
        if (gy < 0 || gy > 27) continue;
        float vv[8][4];
#pragma unroll
        for (int j = 0; j < 8; ++j) {
            const int ci = oct * 8 + j;
            const ushort4 v = *(const ushort4*)(h2b + (size_t)ci * HW + gy * 28 + xq * 4);
            const float A = ws[A2_OFF + ci], Bc = ws[B2_OFF + ci];
            vv[j][0] = qact(fmaxf(0.f, fmaf(bf2f(v.x), A, Bc)), mn3, mx3, inv3, sc3);
            vv[j][1] = qact(fmaxf(0.f, fmaf(bf2f(v.y), A, Bc)), mn3, mx3, inv3, sc3);
            vv[j][2] = qact(fmaxf(0.f, fmaf(bf2f(v.z), A, Bc)), mn3, mx3, inv3, sc3);
            vv[j][3] = qact(fmaxf(0.f, fmaf(bf2f(v.w), A, Bc)), mn3, mx3, inv3, sc3);
        }
#pragma unroll
        for (int xi = 0; xi < 4; ++xi) {
            const int col = xq * 4 + xi + 1;
            const int phys = (oct + col) & 15;
            uint4 pk;
            pk.x = f2bf(vv[0][xi]) | (f2bf(vv[1][xi]) << 16);
            pk.y = f2bf(vv[2][xi]) | (f2bf(vv[3][xi]) << 16);
            pk.z = f2bf(vv[4][xi]) | (f2bf(vv[5][xi]) << 16);
            pk.w = f2bf(vv[6][xi]) | (f2bf(vv[7][xi]) << 16);
            *(uint4*)&lact[((r * 30 + col) * 16 + phys) * 8] = pk;
        }
    }
    __syncthreads();

    const int wv = tid >> 6, lane = tid & 63, r4 = lane & 15, g = lane >> 4;
    int py[2], px[2];
#pragma unroll
    for (int i = 0; i < 2; ++i) {
        const int p = (wv * 2 + i) * 16 + r4;
        py[i] = p / 28; px[i] = p % 28;
    }
    f32x4 acc[2][2];
#pragma unroll
    for (int ct = 0; ct < 2; ++ct)
#pragma unroll
        for (int i = 0; i < 2; ++i) acc[ct][i] = f32x4{0.f, 0.f, 0.f, 0.f};

    const unsigned short* qw2 = (const unsigned short*)(ws + QW2_OFF);
    for (int tap = 0; tap < 9; ++tap) {
        const int dy = tap / 3, dx = tap % 3;
        bf16x8 afr[2][4];
#pragma unroll
        for (int ct = 0; ct < 2; ++ct)
#pragma unroll
            for (int c4 = 0; c4 < 4; ++c4) {
                const int co = ct * 16 + r4;
                afr[ct][c4] = *(const bf16x8*)&qw2[(size_t)co * 1152 + tap * 128 + c4 * 32 + g * 8];
            }
#pragma unroll
        for (int c4 = 0; c4 < 4; ++c4) {
            bf16x8 bfr[2];
#pragma unroll
            for (int i = 0; i < 2; ++i) {
                const int row = py[i] + dy, col = px[i] + dx;
                const int phys = (c4 * 4 + g + col) & 15;
                bfr[i] = *(const bf16x8*)&lact[((row * 30 + col) * 16 + phys) * 8];
            }
#pragma unroll
            for (int ct = 0; ct < 2; ++ct)
#pragma unroll
                for (int i = 0; i < 2; ++i)
                    acc[ct][i] = __builtin_amdgcn_mfma_f32_16x16x32_bf16(afr[ct][c4], bfr[i], acc[ct][i], 0, 0, 0);
        }
    }

#pragma unroll
    for (int ct = 0; ct < 2; ++ct)
#pragma unroll
        for (int i = 0; i < 2; ++i) {
            const int pf = wv * 2 + i;
            if (pf < 7) {
                const int p = pf * 16 + r4;
#pragma unroll
                for (int r = 0; r < 4; ++r) {
                    const int co = ct * 16 + g * 4 + r;
                    out[((size_t)b * C_TOT + 512 + co) * HW + y0 * 28 + p] = acc[ct][i][r];
                }
            }
        }
}

extern "C" void kernel_launch(void* const* d_in, const int* in_sizes, int n_in,
                              void* d_out, int out_size, void* d_ws, size_t ws_size,
                              hipStream_t stream) {
    const float* x       = (const float*)d_in[0];
    const float* bn1_w   = (const float*)d_in[1];
    const float* bn1_b   = (const float*)d_in[2];
    const float* conv1_w = (const float*)d_in[3];
    const float* rbn_w   = (const float*)d_in[4];
    const float* rbn_b   = (const float*)d_in[5];
    const float* conv2_w = (const float*)d_in[6];
    float* out = (float*)d_out;
    float* ws  = (float*)d_ws;   // needs ~27 MB

    k_stats<<<NCOPY + NSTAT + 40, 256, 0, stream>>>(x, conv1_w, conv2_w, out, ws);
    k_prep<<<42, 256, 0, stream>>>(conv1_w, conv2_w, bn1_w, bn1_b, rbn_w, rbn_b, ws);
    k_conv1<<<dim3(7, 64), 256, 0, stream>>>(x, ws);
    k_rbn_combine<<<128, 64, 0, stream>>>(ws);
    k_conv2<<<dim3(7, 64), 256, 0, stream>>>(out, ws);
}

// Round 13
// 118.568 us; speedup vs baseline: 1.0368x; 1.0009x over previous
//
#include <hip/hip_runtime.h>
#include <math.h>

// Dims: x[64,512,28,28] -> out[64,544,28,28] fp32
static constexpr int BB    = 64;
static constexpr int C_IN  = 512;
static constexpr int C_MID = 128;
static constexpr int C_OUT = 32;
static constexpr int C_TOT = 544;
static constexpr int HW    = 784;   // 28*28

// ---- workspace layout (float offsets). ~27 MB ----
static constexpr size_t H2_OFF    = 0;                         // bf16 h2: 64*128*784 ushorts
static constexpr size_t QW1_OFF   = 6422528;                   // bf16 [8][128][64] swizzled
static constexpr size_t QW2_OFF   = QW1_OFF + 65536;           // bf16 [co32][k1152]
static constexpr size_t PSTAT_OFF = QW2_OFF + 49152;           // [512][8][4] {s,s2,mn,mx}
static constexpr size_t BNA_OFF   = PSTAT_OFF + 16384;         // 512
static constexpr size_t BNB_OFF   = BNA_OFF + 512;             // 512
static constexpr size_t A2_OFF    = BNB_OFF + 512;             // 128
static constexpr size_t B2_OFF    = A2_OFF + 128;
static constexpr size_t QRW_OFF   = B2_OFF + 128;
static constexpr size_t QRB_OFF   = QRW_OFF + 128;
static constexpr size_t SCAL_OFF  = QRB_OFF + 128;             // 16: 0=mn1 1=sc1 2=inv1 6=mx1
static constexpr size_t PART_OFF  = SCAL_OFF + 16;             // weight partials: w1[32][2], w2 at +64 [8][2]
static constexpr size_t RP_OFF    = PART_OFF + 128;            // rbn partials [co128][b64][pt7][3]
static constexpr size_t PART2_OFF = RP_OFF + 172032;           // per-channel h3 lo/hi [128][2]

#define DEVFN __device__ __forceinline__

typedef __bf16 bf16x8 __attribute__((ext_vector_type(8)));
typedef float  f32x4  __attribute__((ext_vector_type(4)));

DEVFN float qact(float v, float mn, float mx, float inv, float sc) {
    v = fminf(fmaxf(v, mn), mx);
    return fmaf(rintf((v - mn) * inv), sc, mn);   // rintf == round-half-even == jnp.round
}

DEVFN unsigned f2bf(float f) {                    // fp32 -> bf16 bits, RNE
    unsigned u = __float_as_uint(f);
    return (u + 0x7fffu + ((u >> 16) & 1u)) >> 16;
}

DEVFN float bf2f(unsigned short h) { return __uint_as_float((unsigned)h << 16); }

// ---------- K-copy: pure sequential concat-copy out[:, :512] = x. Launched FIRST (primes L3 with x) ----------
__global__ __launch_bounds__(256) void k_copy(const float* __restrict__ x, float* __restrict__ out) {
    const unsigned t = blockIdx.x * 256 + threadIdx.x;   // 0..802815
#pragma unroll
    for (int i = 0; i < 8; ++i) {                        // 802816*8 = 6,422,528 f4 total
        const unsigned xi = (unsigned)i * 802816u + t;
        const unsigned b = xi / 100352u;                 // f4 per image (x): 512*784/4
        const unsigned r = xi % 100352u;
        const f32x4 v = ((const f32x4*)x)[xi];
        __builtin_nontemporal_store(v, (f32x4*)out + (size_t)b * 106624u + r);  // 544*784/4
    }
}

// ---------- K0: per-channel x stats (4096 blocks, channel-major, L3-hot) + weight partials (40) ----------
__global__ __launch_bounds__(256) void k_stats(const float* __restrict__ x,
                                               const float* __restrict__ conv1_w,
                                               const float* __restrict__ conv2_w,
                                               float* __restrict__ ws) {
    const int bid = blockIdx.x, tid = threadIdx.x;
    __shared__ float r0[256], r1[256], r2[256], r3[256];

    if (bid < 4096) {                              // x stats: (c, 8-image group)
        const int c = bid >> 3, bg = bid & 7;
        float s = 0.f, s2 = 0.f, mn = INFINITY, mx = -INFINITY;
        for (int i = tid; i < 1568; i += 256) {
            const int b = bg * 8 + i / 196, j = i % 196;
            const float4 v = ((const float4*)(x + ((size_t)b * C_IN + c) * HW))[j];
            s  += (v.x + v.y) + (v.z + v.w);
            s2 += v.x * v.x + v.y * v.y + v.z * v.z + v.w * v.w;
            mn = fminf(mn, fminf(fminf(v.x, v.y), fminf(v.z, v.w)));
            mx = fmaxf(mx, fmaxf(fmaxf(v.x, v.y), fmaxf(v.z, v.w)));
        }
        r0[tid] = s; r1[tid] = s2; r2[tid] = mn; r3[tid] = mx;
        __syncthreads();
        for (int off = 128; off > 0; off >>= 1) {
            if (tid < off) {
                r0[tid] += r0[tid + off];
                r1[tid] += r1[tid + off];
                r2[tid] = fminf(r2[tid], r2[tid + off]);
                r3[tid] = fmaxf(r3[tid], r3[tid + off]);
            }
            __syncthreads();
        }
        if (tid == 0) {
            float* p = ws + PSTAT_OFF + ((size_t)c * 8 + bg) * 4;
            p[0] = r0[0]; p[1] = r1[0]; p[2] = r2[0]; p[3] = r3[0];
        }
    } else {                                       // weight min/max -> fixed partial slots
        const int wb = bid - 4096;                 // 0..39
        float mn = INFINITY, mx = -INFINITY;
        if (wb < 32) {
            const float4* src = (const float4*)conv1_w + (size_t)wb * 512;
            for (int i = tid; i < 512; i += 256) {
                const float4 v = src[i];
                mn = fminf(mn, fminf(fminf(v.x, v.y), fminf(v.z, v.w)));
                mx = fmaxf(mx, fmaxf(fmaxf(v.x, v.y), fmaxf(v.z, v.w)));
            }
        } else {
            const float4* src = (const float4*)conv2_w + (size_t)(wb - 32) * 1152;
            for (int i = tid; i < 1152; i += 256) {
                const float4 v = src[i];
                mn = fminf(mn, fminf(fminf(v.x, v.y), fminf(v.z, v.w)));
                mx = fmaxf(mx, fmaxf(fmaxf(v.x, v.y), fmaxf(v.z, v.w)));
            }
        }
        r2[tid] = mn; r3[tid] = mx;
        __syncthreads();
        for (int off = 128; off > 0; off >>= 1) {
            if (tid < off) { r2[tid] = fminf(r2[tid], r2[tid + off]); r3[tid] = fmaxf(r3[tid], r3[tid + off]); }
            __syncthreads();
        }
        if (tid == 0) {
            float* p = (wb < 32) ? ws + PART_OFF + (size_t)wb * 2
                                 : ws + PART_OFF + 64 + (size_t)(wb - 32) * 2;
            p[0] = r2[0]; p[1] = r3[0];
        }
    }
}

// ---------- K1: prep — weight quantize, BN affine + h1 range, rbn quantize ----------
__global__ __launch_bounds__(256) void k_prep(const float* __restrict__ conv1_w,
                                              const float* __restrict__ conv2_w,
                                              const float* __restrict__ bn1_w,
                                              const float* __restrict__ bn1_b,
                                              const float* __restrict__ rbn_w,
                                              const float* __restrict__ rbn_b,
                                              float* __restrict__ ws) {
    const int b = blockIdx.x, tid = threadIdx.x;
    __shared__ float ra[256], rb[256];
    __shared__ float s_mn, s_sc;

    if (b < 32) {                                  // conv1_w -> bf16 swizzled [ks][co][k64]
        ra[tid] = tid < 32 ? ws[PART_OFF + tid * 2] : INFINITY;
        rb[tid] = tid < 32 ? ws[PART_OFF + tid * 2 + 1] : -INFINITY;
        __syncthreads();
        for (int off = 128; off > 0; off >>= 1) {
            if (tid < off) { ra[tid] = fminf(ra[tid], ra[tid + off]); rb[tid] = fmaxf(rb[tid], rb[tid + off]); }
            __syncthreads();
        }
        if (tid == 0) { s_mn = ra[0]; s_sc = fmaxf((rb[0] - ra[0]) / 255.f, 1e-8f); }
        __syncthreads();
        const float mnw = s_mn, scw = s_sc;
        unsigned short* qw = (unsigned short*)(ws + QW1_OFF);
        const int base = b * 2048;
#pragma unroll
        for (int t = 0; t < 8; ++t) {
            const int i = base + t * 256 + tid;
            const int co = i >> 9, k = i & 511;
            const float v = conv1_w[i];
            const float qv = fmaf(rintf((v - mnw) / scw), scw, mnw);
            const int ks = k >> 6, kc = (k >> 3) & 7, klo = k & 7;
            qw[(((size_t)ks * 128 + co) << 6) + (((kc ^ (co & 7)) << 3) | klo)] = (unsigned short)f2bf(qv);
        }
    } else if (b < 40) {                           // conv2_w -> bf16 [co][k = tap*128 + ci]
        ra[tid] = tid < 8 ? ws[PART_OFF + 64 + tid * 2] : INFINITY;
        rb[tid] = tid < 8 ? ws[PART_OFF + 64 + tid * 2 + 1] : -INFINITY;
        __syncthreads();
        for (int off = 128; off > 0; off >>= 1) {
            if (tid < off) { ra[tid] = fminf(ra[tid], ra[tid + off]); rb[tid] = fmaxf(rb[tid], rb[tid + off]); }
            __syncthreads();
        }
        if (tid == 0) { s_mn = ra[0]; s_sc = fmaxf((rb[0] - ra[0]) / 255.f, 1e-8f); }
        __syncthreads();
        const float mnw = s_mn, scw = s_sc;
        unsigned short* qw2 = (unsigned short*)(ws + QW2_OFF);
        const int base = (b - 32) * 4608;
        for (int i2 = tid; i2 < 4608; i2 += 256) {
            const int i = base + i2;
            const int co = i / 1152, r = i % 1152, ci = r / 9, tap = r % 9;
            const float v = conv2_w[i];
            const float qv = fmaf(rintf((v - mnw) / scw), scw, mnw);
            qw2[(size_t)co * 1152 + tap * 128 + ci] = (unsigned short)f2bf(qv);
        }
    } else if (b == 40) {                          // BN affine + global h1 range
        float lmn = INFINITY, lmx = -INFINITY;
        for (int c = tid; c < 512; c += 256) {
            const float* p = ws + PSTAT_OFF + (size_t)c * 32;
            float s = 0.f, s2 = 0.f, cmn = INFINITY, cmx = -INFINITY;
            for (int g = 0; g < 8; ++g) {
                s += p[g * 4 + 0]; s2 += p[g * 4 + 1];
                cmn = fminf(cmn, p[g * 4 + 2]); cmx = fmaxf(cmx, p[g * 4 + 3]);
            }
            const float n = 50176.f;
            const float mean = s / n;
            const float var  = s2 / n - mean * mean;
            const float rstd = rsqrtf(var + 1e-5f);
            const float A  = rstd * bn1_w[c];
            const float Bc = bn1_b[c] - mean * A;
            ws[BNA_OFF + c] = A; ws[BNB_OFF + c] = Bc;
            const float v1 = A * cmn + Bc, v2 = A * cmx + Bc;
            lmn = fminf(lmn, fmaxf(0.f, fminf(v1, v2)));
            lmx = fmaxf(lmx, fmaxf(0.f, fmaxf(v1, v2)));
        }
        ra[tid] = lmn; rb[tid] = lmx;
        __syncthreads();
        for (int off = 128; off > 0; off >>= 1) {
            if (tid < off) { ra[tid] = fminf(ra[tid], ra[tid + off]); rb[tid] = fmaxf(rb[tid], rb[tid + off]); }
            __syncthreads();
        }
        if (tid == 0) {
            const float mn1 = ra[0], mx1 = rb[0];
            const float sc = fmaxf((mx1 - mn1) / 255.f, 1e-8f);
            ws[SCAL_OFF + 0] = mn1; ws[SCAL_OFF + 1] = sc; ws[SCAL_OFF + 2] = 1.f / sc; ws[SCAL_OFF + 6] = mx1;
        }
    } else {                                       // b == 41: rbn_w / rbn_b quantize
        for (int which = 0; which < 2; ++which) {
            const float* src = which ? rbn_b : rbn_w;
            const size_t dst = which ? QRB_OFF : QRW_OFF;
            float v = 0.f;
            ra[tid] = INFINITY; rb[tid] = -INFINITY;
            if (tid < 128) { v = src[tid]; ra[tid] = v; rb[tid] = v; }
            __syncthreads();
            for (int off = 128; off > 0; off >>= 1) {
                if (tid < off) { ra[tid] = fminf(ra[tid], ra[tid + off]); rb[tid] = fmaxf(rb[tid], rb[tid + off]); }
                __syncthreads();
            }
            if (tid == 0) { s_mn = ra[0]; s_sc = fmaxf((rb[0] - ra[0]) / 255.f, 1e-8f); }
            __syncthreads();
            if (tid < 128) ws[dst + tid] = fmaf(rintf((v - s_mn) / s_sc), s_sc, s_mn);
            __syncthreads();
        }
    }
}

// ---------- K2: 1x1 conv MFMA GEMM (M=128), lean: x L3-read + bf16 h2 write + RBN partials ----------
__global__ __launch_bounds__(256, 2) void k_conv1(const float* __restrict__ x,
                                                  float* __restrict__ ws) {
    __shared__ __align__(16) unsigned short wt[128 * 64];    // 16 KB
    __shared__ __align__(16) unsigned short ht[112 * 64];    // 14 KB
    const int tid = threadIdx.x;
    const int pt = blockIdx.x, b = blockIdx.y;
    const int p0 = pt * 112;
    const float mn1 = ws[SCAL_OFF + 0], sc1 = ws[SCAL_OFF + 1];
    const float inv1 = ws[SCAL_OFF + 2];
    const unsigned short* qw1 = (const unsigned short*)(ws + QW1_OFF);
    const float* xb = x + (size_t)b * C_IN * HW;

    const int o = tid & 7, q = tid >> 3;
    const int wv = tid >> 6, g = (tid >> 4) & 3, r4 = tid & 15;

    f32x4 acc[2][7];
#pragma unroll
    for (int i = 0; i < 2; ++i)
#pragma unroll
        for (int j = 0; j < 7; ++j) acc[i][j] = f32x4{0.f, 0.f, 0.f, 0.f};

    f32x4 xreg[8];
    if (tid < 224) {
#pragma unroll
        for (int j = 0; j < 8; ++j)
            xreg[j] = *(const f32x4*)(xb + (size_t)(o * 8 + j) * HW + p0 + q * 4);
    }

    for (int ks = 0; ks < 8; ++ks) {
        const float4* wsrc = (const float4*)(qw1 + (size_t)ks * 8192);
        float4* wdst = (float4*)wt;
#pragma unroll
        for (int i = 0; i < 4; ++i) wdst[tid + i * 256] = wsrc[tid + i * 256];

        if (tid < 224) {
            const int ci0 = ks * 64 + o * 8;
            float vv[8][4];
#pragma unroll
            for (int j = 0; j < 8; ++j) {
                const f32x4 v = xreg[j];
                const float A = ws[BNA_OFF + ci0 + j], Bc = ws[BNB_OFF + ci0 + j];
                vv[j][0] = fmaf(rintf((fmaxf(fmaf(v.x, A, Bc), 0.f) - mn1) * inv1), sc1, mn1);
                vv[j][1] = fmaf(rintf((fmaxf(fmaf(v.y, A, Bc), 0.f) - mn1) * inv1), sc1, mn1);
                vv[j][2] = fmaf(rintf((fmaxf(fmaf(v.z, A, Bc), 0.f) - mn1) * inv1), sc1, mn1);
                vv[j][3] = fmaf(rintf((fmaxf(fmaf(v.w, A, Bc), 0.f) - mn1) * inv1), sc1, mn1);
            }
            if (ks < 7) {
                const int ci0n = (ks + 1) * 64 + o * 8;
#pragma unroll
                for (int j = 0; j < 8; ++j)
                    xreg[j] = *(const f32x4*)(xb + (size_t)(ci0n + j) * HW + p0 + q * 4);
            }
#pragma unroll
            for (int r = 0; r < 4; ++r) {
                const int p = q * 4 + r;
                uint4 pk;
                pk.x = f2bf(vv[0][r]) | (f2bf(vv[1][r]) << 16);
                pk.y = f2bf(vv[2][r]) | (f2bf(vv[3][r]) << 16);
                pk.z = f2bf(vv[4][r]) | (f2bf(vv[5][r]) << 16);
                pk.w = f2bf(vv[6][r]) | (f2bf(vv[7][r]) << 16);
                *(uint4*)&ht[p * 64 + ((o ^ (p & 7)) << 3)] = pk;
            }
        }
        __syncthreads();

#pragma unroll
        for (int ksub = 0; ksub < 2; ++ksub) {
            const int kk = ksub * 4 + g;
            bf16x8 af[2], bfr[7];
#pragma unroll
            for (int ct = 0; ct < 2; ++ct) {
                const int co = wv * 32 + ct * 16 + r4;
                af[ct] = *(const bf16x8*)&wt[co * 64 + ((kk ^ (co & 7)) << 3)];
            }
#pragma unroll
            for (int pf = 0; pf < 7; ++pf) {
                const int p = pf * 16 + r4;
                bfr[pf] = *(const bf16x8*)&ht[p * 64 + ((kk ^ (p & 7)) << 3)];
            }
#pragma unroll
            for (int ct = 0; ct < 2; ++ct)
#pragma unroll
                for (int pf = 0; pf < 7; ++pf)
                    acc[ct][pf] = __builtin_amdgcn_mfma_f32_16x16x32_bf16(af[ct], bfr[pf], acc[ct][pf], 0, 0, 0);
        }
        __syncthreads();
    }

    unsigned short* hb = (unsigned short*)(ws + H2_OFF) + (size_t)b * C_MID * HW;
#pragma unroll
    for (int ct = 0; ct < 2; ++ct) {
        const int co0 = wv * 32 + ct * 16 + g * 4;
#pragma unroll
        for (int pf = 0; pf < 7; ++pf) {
            const int p = p0 + pf * 16 + r4;
#pragma unroll
            for (int r = 0; r < 4; ++r)
                hb[(size_t)(co0 + r) * HW + p] = (unsigned short)f2bf(acc[ct][pf][r]);
        }
    }

#pragma unroll
    for (int ct = 0; ct < 2; ++ct)
#pragma unroll
        for (int r = 0; r < 4; ++r) {
            float s = 0.f, mn = INFINITY, mx = -INFINITY;
#pragma unroll
            for (int pf = 0; pf < 7; ++pf) {
                const float v = acc[ct][pf][r];
                s += v; mn = fminf(mn, v); mx = fmaxf(mx, v);
            }
#pragma unroll
            for (int m = 1; m < 16; m <<= 1) {
                s  += __shfl_xor(s, m, 64);
                mn  = fminf(mn, __shfl_xor(mn, m, 64));
                mx  = fmaxf(mx, __shfl_xor(mx, m, 64));
            }
            if (r4 == 0) {
                const int co = wv * 32 + ct * 16 + g * 4 + r;
                float* dst = ws + RP_OFF + (((size_t)co * 64 + b) * 7 + pt) * 3;
                dst[0] = s; dst[1] = mn; dst[2] = mx;
            }
        }
}

// ---------- K3: combine RBN partials -> per-channel affine + h3 endpoints (PART2) ----------
__global__ __launch_bounds__(64) void k_rbn_combine(float* __restrict__ ws) {
    const int c = blockIdx.x, t = threadIdx.x;
    const int ch = t >> 2, sub = t & 3;
    const int b = ch * 4 + sub;
    const float* rp = ws + RP_OFF + ((size_t)c * 64 + b) * 21;
    float s = 0.f, mn = INFINITY, mx = -INFINITY;
#pragma unroll
    for (int pt = 0; pt < 7; ++pt) {
        s += rp[pt * 3 + 0];
        mn = fminf(mn, rp[pt * 3 + 1]);
        mx = fmaxf(mx, rp[pt * 3 + 2]);
    }
#pragma unroll
    for (int m = 1; m < 4; m <<= 1) {
        s  += __shfl_xor(s, m, 64);
        mn  = fminf(mn, __shfl_xor(mn, m, 64));
        mx  = fmaxf(mx, __shfl_xor(mx, m, 64));
    }
    float smx = mx, smn = mn, stot = s, gmn = mn, gmx = mx;
#pragma unroll
    for (int m = 4; m < 64; m <<= 1) {
        smx  += __shfl_xor(smx, m, 64);
        smn  += __shfl_xor(smn, m, 64);
        stot += __shfl_xor(stot, m, 64);
        gmn   = fminf(gmn, __shfl_xor(gmn, m, 64));
        gmx   = fmaxf(gmx, __shfl_xor(gmx, m, 64));
    }
    if (t == 0) {
        const float mm = smx * (1.f / 16.f), mnm = smn * (1.f / 16.f);
        const float mean = stot / 50176.f;
        const double PI_D = 3.14159265358979323846;
        const double sfd = 0.175 * (1.0 + sqrt(PI_D * log(4.0))) / sqrt(2.0 * log(3136.0));
        const float scale = 1.f / ((mm - mnm) * (float)sfd + 1e-5f);
        const float A  = scale * ws[QRW_OFF + c];
        const float Bc = ws[QRB_OFF + c] - mean * A;
        ws[A2_OFF + c] = A; ws[B2_OFF + c] = Bc;
        const float v1 = A * gmn + Bc, v2 = A * gmx + Bc;
        ws[PART2_OFF + c * 2 + 0] = fmaxf(0.f, fminf(v1, v2));
        ws[PART2_OFF + c * 2 + 1] = fmaxf(0.f, fmaxf(v1, v2));
    }
}

// ---------- K4: 3x3 conv via MFMA implicit im2col, 256 threads, h2 bf16, h3 range from PART2 ----------
__global__ __launch_bounds__(256, 2) void k_conv2(float* __restrict__ out, const float* __restrict__ ws) {
    __shared__ __align__(16) unsigned short lact[7 * 30 * 128];   // 52.5 KB
    __shared__ float sra[128], srb[128];
    __shared__ float s_mn3, s_mx3, s_sc3, s_inv3;
    const int tid = threadIdx.x;
    const int pt = blockIdx.x, b = blockIdx.y;
    const int y0 = pt * 4;

    if (tid < 128) { sra[tid] = ws[PART2_OFF + tid * 2]; srb[tid] = ws[PART2_OFF + tid * 2 + 1]; }
    __syncthreads();
    for (int off = 64; off > 0; off >>= 1) {
        if (tid < off) { sra[tid] = fminf(sra[tid], sra[tid + off]); srb[tid] = fmaxf(srb[tid], srb[tid + off]); }
        __syncthreads();
    }
    if (tid == 0) {
        const float mn3 = sra[0], mx3 = srb[0];
        const float sc = fmaxf((mx3 - mn3) / 255.f, 1e-8f);
        s_mn3 = mn3; s_mx3 = mx3; s_sc3 = sc; s_inv3 = 1.f / sc;
    }
    {
        const uint4 z = {0u, 0u, 0u, 0u};
        uint4* lp = (uint4*)lact;
        for (int i = tid; i < 3360; i += 256) lp[i] = z;
    }
    __syncthreads();
    const float mn3 = s_mn3, mx3 = s_mx3, sc3 = s_sc3, inv3 = s_inv3;

    const unsigned short* h2b = (const unsigned short*)(ws + H2_OFF) + (size_t)b * C_MID * HW;
    for (int task = tid; task < 672; task += 256) {
        const int oct = task / 42, rem = task % 42, r = rem / 7, xq = rem % 7;
        const int gy = y0 - 1 + r;
        if (gy < 0 || gy > 27) continue;
        float vv[8][4];
#pragma unroll
        for (int j = 0; j < 8; ++j) {
            const int ci = oct * 8 + j;
            const ushort4 v = *(const ushort4*)(h2b + (size_t)ci * HW + gy * 28 + xq * 4);
            const float A = ws[A2_OFF + ci], Bc = ws[B2_OFF + ci];
            vv[j][0] = qact(fmaxf(0.f, fmaf(bf2f(v.x), A, Bc)), mn3, mx3, inv3, sc3);
            vv[j][1] = qact(fmaxf(0.f, fmaf(bf2f(v.y), A, Bc)), mn3, mx3, inv3, sc3);
            vv[j][2] = qact(fmaxf(0.f, fmaf(bf2f(v.z), A, Bc)), mn3, mx3, inv3, sc3);
            vv[j][3] = qact(fmaxf(0.f, fmaf(bf2f(v.w), A, Bc)), mn3, mx3, inv3, sc3);
        }
#pragma unroll
        for (int xi = 0; xi < 4; ++xi) {
            const int col = xq * 4 + xi + 1;
            const int phys = (oct + col) & 15;
            uint4 pk;
            pk.x = f2bf(vv[0][xi]) | (f2bf(vv[1][xi]) << 16);
            pk.y = f2bf(vv[2][xi]) | (f2bf(vv[3][xi]) << 16);
            pk.z = f2bf(vv[4][xi]) | (f2bf(vv[5][xi]) << 16);
            pk.w = f2bf(vv[6][xi]) | (f2bf(vv[7][xi]) << 16);
            *(uint4*)&lact[((r * 30 + col) * 16 + phys) * 8] = pk;
        }
    }
    __syncthreads();

    const int wv = tid >> 6, lane = tid & 63, r4 = lane & 15, g = lane >> 4;
    int py[2], px[2];
#pragma unroll
    for (int i = 0; i < 2; ++i) {
        const int p = (wv * 2 + i) * 16 + r4;
        py[i] = p / 28; px[i] = p % 28;
    }
    f32x4 acc[2][2];
#pragma unroll
    for (int ct = 0; ct < 2; ++ct)
#pragma unroll
        for (int i = 0; i < 2; ++i) acc[ct][i] = f32x4{0.f, 0.f, 0.f, 0.f};

    const unsigned short* qw2 = (const unsigned short*)(ws + QW2_OFF);
    for (int tap = 0; tap < 9; ++tap) {
        const int dy = tap / 3, dx = tap % 3;
        bf16x8 afr[2][4];
#pragma unroll
        for (int ct = 0; ct < 2; ++ct)
#pragma unroll
            for (int c4 = 0; c4 < 4; ++c4) {
                const int co = ct * 16 + r4;
                afr[ct][c4] = *(const bf16x8*)&qw2[(size_t)co * 1152 + tap * 128 + c4 * 32 + g * 8];
            }
#pragma unroll
        for (int c4 = 0; c4 < 4; ++c4) {
            bf16x8 bfr[2];
#pragma unroll
            for (int i = 0; i < 2; ++i) {
                const int row = py[i] + dy, col = px[i] + dx;
                const int phys = (c4 * 4 + g + col) & 15;
                bfr[i] = *(const bf16x8*)&lact[((row * 30 + col) * 16 + phys) * 8];
            }
#pragma unroll
            for (int ct = 0; ct < 2; ++ct)
#pragma unroll
                for (int i = 0; i < 2; ++i)
                    acc[ct][i] = __builtin_amdgcn_mfma_f32_16x16x32_bf16(afr[ct][c4], bfr[i], acc[ct][i], 0, 0, 0);
        }
    }

#pragma unroll
    for (int ct = 0; ct < 2; ++ct)
#pragma unroll
        for (int i = 0; i < 2; ++i) {
            const int pf = wv * 2 + i;
            if (pf < 7) {
                const int p = pf * 16 + r4;
#pragma unroll
                for (int r = 0; r < 4; ++r) {
                    const int co = ct * 16 + g * 4 + r;
                    out[((size_t)b * C_TOT + 512 + co) * HW + y0 * 28 + p] = acc[ct][i][r];
                }
            }
        }
}

extern "C" void kernel_launch(void* const* d_in, const int* in_sizes, int n_in,
                              void* d_out, int out_size, void* d_ws, size_t ws_size,
                              hipStream_t stream) {
    const float* x       = (const float*)d_in[0];
    const float* bn1_w   = (const float*)d_in[1];
    const float* bn1_b   = (const float*)d_in[2];
    const float* conv1_w = (const float*)d_in[3];
    const float* rbn_w   = (const float*)d_in[4];
    const float* rbn_b   = (const float*)d_in[5];
    const float* conv2_w = (const float*)d_in[6];
    float* out = (float*)d_out;
    float* ws  = (float*)d_ws;   // needs ~27 MB

    k_copy<<<3136, 256, 0, stream>>>(x, out);
    k_stats<<<4136, 256, 0, stream>>>(x, conv1_w, conv2_w, ws);
    k_prep<<<42, 256, 0, stream>>>(conv1_w, conv2_w, bn1_w, bn1_b, rbn_w, rbn_b, ws);
    k_conv1<<<dim3(7, 64), 256, 0, stream>>>(x, ws);
    k_rbn_combine<<<128, 64, 0, stream>>>(ws);
    k_conv2<<<dim3(7, 64), 256, 0, stream>>>(out, ws);
}

// Round 14
// 103.165 us; speedup vs baseline: 1.1916x; 1.1493x over previous
//
#include <hip/hip_runtime.h>
#include <math.h>

// Dims: x[64,512,28,28] -> out[64,544,28,28] fp32
static constexpr int BB    = 64;
static constexpr int C_IN  = 512;
static constexpr int C_MID = 128;
static constexpr int C_OUT = 32;
static constexpr int C_TOT = 544;
static constexpr int HW    = 784;   // 28*28

// ---- workspace layout (float offsets). ~27 MB ----
static constexpr size_t H2_OFF    = 0;                         // bf16 h2: 64*128*784 ushorts
static constexpr size_t QW1_OFF   = 6422528;                   // bf16 [8][128][64] swizzled
static constexpr size_t QW2_OFF   = QW1_OFF + 65536;           // bf16 [co32][k1152]
static constexpr size_t PSTAT_OFF = QW2_OFF + 49152;           // [512][8][4] {s,s2,mn,mx}
static constexpr size_t BNA_OFF   = PSTAT_OFF + 16384;         // 512
static constexpr size_t BNB_OFF   = BNA_OFF + 512;             // 512
static constexpr size_t A2_OFF    = BNB_OFF + 512;             // 128
static constexpr size_t B2_OFF    = A2_OFF + 128;
static constexpr size_t QRW_OFF   = B2_OFF + 128;
static constexpr size_t QRB_OFF   = QRW_OFF + 128;
static constexpr size_t SCAL_OFF  = QRB_OFF + 128;             // 16: 0=mn1 1=sc1 2=inv1 6=mx1
static constexpr size_t PART_OFF  = SCAL_OFF + 16;             // weight partials: w1[32][2], w2 at +64 [8][2]
static constexpr size_t RP_OFF    = PART_OFF + 128;            // rbn partials [co128][b64][pt7][3]
static constexpr size_t PART2_OFF = RP_OFF + 172032;           // per-channel h3 lo/hi [128][2]

#define DEVFN __device__ __forceinline__

typedef __bf16 bf16x8 __attribute__((ext_vector_type(8)));
typedef float  f32x4  __attribute__((ext_vector_type(4)));

DEVFN float qact(float v, float mn, float mx, float inv, float sc) {
    v = fminf(fmaxf(v, mn), mx);
    return fmaf(rintf((v - mn) * inv), sc, mn);   // rintf == round-half-even == jnp.round
}

DEVFN unsigned f2bf(float f) {                    // fp32 -> bf16 bits, RNE
    unsigned u = __float_as_uint(f);
    return (u + 0x7fffu + ((u >> 16) & 1u)) >> 16;
}

DEVFN float bf2f(unsigned short h) { return __uint_as_float((unsigned)h << 16); }

// ---------- K0: per-channel x stats (4096 blocks, XCD-contiguous channel ranges) + weight partials (40) ----------
__global__ __launch_bounds__(256) void k_stats(const float* __restrict__ x,
                                               const float* __restrict__ conv1_w,
                                               const float* __restrict__ conv2_w,
                                               float* __restrict__ ws) {
    const int bid = blockIdx.x, tid = threadIdx.x;
    __shared__ float r0[256], r1[256], r2[256], r3[256];

    if (bid < 4096) {                              // x stats: XCD k owns channels [64k, 64k+64)
        const int xcd = bid & 7, slot = bid >> 3;
        const int c = xcd * 64 + (slot & 63), bg = slot >> 6;
        float s = 0.f, s2 = 0.f, mn = INFINITY, mx = -INFINITY;
        for (int i = tid; i < 1568; i += 256) {
            const int b = bg * 8 + i / 196, j = i % 196;
            const float4 v = ((const float4*)(x + ((size_t)b * C_IN + c) * HW))[j];
            s  += (v.x + v.y) + (v.z + v.w);
            s2 += v.x * v.x + v.y * v.y + v.z * v.z + v.w * v.w;
            mn = fminf(mn, fminf(fminf(v.x, v.y), fminf(v.z, v.w)));
            mx = fmaxf(mx, fmaxf(fmaxf(v.x, v.y), fmaxf(v.z, v.w)));
        }
        r0[tid] = s; r1[tid] = s2; r2[tid] = mn; r3[tid] = mx;
        __syncthreads();
        for (int off = 128; off > 0; off >>= 1) {
            if (tid < off) {
                r0[tid] += r0[tid + off];
                r1[tid] += r1[tid + off];
                r2[tid] = fminf(r2[tid], r2[tid + off]);
                r3[tid] = fmaxf(r3[tid], r3[tid + off]);
            }
            __syncthreads();
        }
        if (tid == 0) {
            float* p = ws + PSTAT_OFF + ((size_t)c * 8 + bg) * 4;
            p[0] = r0[0]; p[1] = r1[0]; p[2] = r2[0]; p[3] = r3[0];
        }
    } else {                                       // weight min/max -> fixed partial slots
        const int wb = bid - 4096;                 // 0..39
        float mn = INFINITY, mx = -INFINITY;
        if (wb < 32) {
            const float4* src = (const float4*)conv1_w + (size_t)wb * 512;
            for (int i = tid; i < 512; i += 256) {
                const float4 v = src[i];
                mn = fminf(mn, fminf(fminf(v.x, v.y), fminf(v.z, v.w)));
                mx = fmaxf(mx, fmaxf(fmaxf(v.x, v.y), fmaxf(v.z, v.w)));
            }
        } else {
            const float4* src = (const float4*)conv2_w + (size_t)(wb - 32) * 1152;
            for (int i = tid; i < 1152; i += 256) {
                const float4 v = src[i];
                mn = fminf(mn, fminf(fminf(v.x, v.y), fminf(v.z, v.w)));
                mx = fmaxf(mx, fmaxf(fmaxf(v.x, v.y), fmaxf(v.z, v.w)));
            }
        }
        r2[tid] = mn; r3[tid] = mx;
        __syncthreads();
        for (int off = 128; off > 0; off >>= 1) {
            if (tid < off) { r2[tid] = fminf(r2[tid], r2[tid + off]); r3[tid] = fmaxf(r3[tid], r3[tid + off]); }
            __syncthreads();
        }
        if (tid == 0) {
            float* p = (wb < 32) ? ws + PART_OFF + (size_t)wb * 2
                                 : ws + PART_OFF + 64 + (size_t)(wb - 32) * 2;
            p[0] = r2[0]; p[1] = r3[0];
        }
    }
}

// ---------- K1: prep — weight quantize, BN affine + h1 range, rbn quantize ----------
__global__ __launch_bounds__(256) void k_prep(const float* __restrict__ conv1_w,
                                              const float* __restrict__ conv2_w,
                                              const float* __restrict__ bn1_w,
                                              const float* __restrict__ bn1_b,
                                              const float* __restrict__ rbn_w,
                                              const float* __restrict__ rbn_b,
                                              float* __restrict__ ws) {
    const int b = blockIdx.x, tid = threadIdx.x;
    __shared__ float ra[256], rb[256];
    __shared__ float s_mn, s_sc;

    if (b < 32) {                                  // conv1_w -> bf16 swizzled [ks][co][k64]
        ra[tid] = tid < 32 ? ws[PART_OFF + tid * 2] : INFINITY;
        rb[tid] = tid < 32 ? ws[PART_OFF + tid * 2 + 1] : -INFINITY;
        __syncthreads();
        for (int off = 128; off > 0; off >>= 1) {
            if (tid < off) { ra[tid] = fminf(ra[tid], ra[tid + off]); rb[tid] = fmaxf(rb[tid], rb[tid + off]); }
            __syncthreads();
        }
        if (tid == 0) { s_mn = ra[0]; s_sc = fmaxf((rb[0] - ra[0]) / 255.f, 1e-8f); }
        __syncthreads();
        const float mnw = s_mn, scw = s_sc;
        unsigned short* qw = (unsigned short*)(ws + QW1_OFF);
        const int base = b * 2048;
#pragma unroll
        for (int t = 0; t < 8; ++t) {
            const int i = base + t * 256 + tid;
            const int co = i >> 9, k = i & 511;
            const float v = conv1_w[i];
            const float qv = fmaf(rintf((v - mnw) / scw), scw, mnw);
            const int ks = k >> 6, kc = (k >> 3) & 7, klo = k & 7;
            qw[(((size_t)ks * 128 + co) << 6) + (((kc ^ (co & 7)) << 3) | klo)] = (unsigned short)f2bf(qv);
        }
    } else if (b < 40) {                           // conv2_w -> bf16 [co][k = tap*128 + ci]
        ra[tid] = tid < 8 ? ws[PART_OFF + 64 + tid * 2] : INFINITY;
        rb[tid] = tid < 8 ? ws[PART_OFF + 64 + tid * 2 + 1] : -INFINITY;
        __syncthreads();
        for (int off = 128; off > 0; off >>= 1) {
            if (tid < off) { ra[tid] = fminf(ra[tid], ra[tid + off]); rb[tid] = fmaxf(rb[tid], rb[tid + off]); }
            __syncthreads();
        }
        if (tid == 0) { s_mn = ra[0]; s_sc = fmaxf((rb[0] - ra[0]) / 255.f, 1e-8f); }
        __syncthreads();
        const float mnw = s_mn, scw = s_sc;
        unsigned short* qw2 = (unsigned short*)(ws + QW2_OFF);
        const int base = (b - 32) * 4608;
        for (int i2 = tid; i2 < 4608; i2 += 256) {
            const int i = base + i2;
            const int co = i / 1152, r = i % 1152, ci = r / 9, tap = r % 9;
            const float v = conv2_w[i];
            const float qv = fmaf(rintf((v - mnw) / scw), scw, mnw);
            qw2[(size_t)co * 1152 + tap * 128 + ci] = (unsigned short)f2bf(qv);
        }
    } else if (b == 40) {                          // BN affine + global h1 range
        float lmn = INFINITY, lmx = -INFINITY;
        for (int c = tid; c < 512; c += 256) {
            const float* p = ws + PSTAT_OFF + (size_t)c * 32;
            float s = 0.f, s2 = 0.f, cmn = INFINITY, cmx = -INFINITY;
            for (int g = 0; g < 8; ++g) {
                s += p[g * 4 + 0]; s2 += p[g * 4 + 1];
                cmn = fminf(cmn, p[g * 4 + 2]); cmx = fmaxf(cmx, p[g * 4 + 3]);
            }
            const float n = 50176.f;
            const float mean = s / n;
            const float var  = s2 / n - mean * mean;
            const float rstd = rsqrtf(var + 1e-5f);
            const float A  = rstd * bn1_w[c];
            const float Bc = bn1_b[c] - mean * A;
            ws[BNA_OFF + c] = A; ws[BNB_OFF + c] = Bc;
            const float v1 = A * cmn + Bc, v2 = A * cmx + Bc;
            lmn = fminf(lmn, fmaxf(0.f, fminf(v1, v2)));
            lmx = fmaxf(lmx, fmaxf(0.f, fmaxf(v1, v2)));
        }
        ra[tid] = lmn; rb[tid] = lmx;
        __syncthreads();
        for (int off = 128; off > 0; off >>= 1) {
            if (tid < off) { ra[tid] = fminf(ra[tid], ra[tid + off]); rb[tid] = fmaxf(rb[tid], rb[tid + off]); }
            __syncthreads();
        }
        if (tid == 0) {
            const float mn1 = ra[0], mx1 = rb[0];
            const float sc = fmaxf((mx1 - mn1) / 255.f, 1e-8f);
            ws[SCAL_OFF + 0] = mn1; ws[SCAL_OFF + 1] = sc; ws[SCAL_OFF + 2] = 1.f / sc; ws[SCAL_OFF + 6] = mx1;
        }
    } else {                                       // b == 41: rbn_w / rbn_b quantize
        for (int which = 0; which < 2; ++which) {
            const float* src = which ? rbn_b : rbn_w;
            const size_t dst = which ? QRB_OFF : QRW_OFF;
            float v = 0.f;
            ra[tid] = INFINITY; rb[tid] = -INFINITY;
            if (tid < 128) { v = src[tid]; ra[tid] = v; rb[tid] = v; }
            __syncthreads();
            for (int off = 128; off > 0; off >>= 1) {
                if (tid < off) { ra[tid] = fminf(ra[tid], ra[tid + off]); rb[tid] = fmaxf(rb[tid], rb[tid + off]); }
                __syncthreads();
            }
            if (tid == 0) { s_mn = ra[0]; s_sc = fmaxf((rb[0] - ra[0]) / 255.f, 1e-8f); }
            __syncthreads();
            if (tid < 128) ws[dst + tid] = fmaf(rintf((v - s_mn) / s_sc), s_sc, s_mn);
            __syncthreads();
        }
    }
}

// ---------- K2: 1x1 conv MFMA GEMM (M=128), fused concat-copy (NT) + bf16 h2 + RBN partials ----------
__global__ __launch_bounds__(256, 2) void k_conv1(const float* __restrict__ x,
                                                  float* __restrict__ out,
                                                  float* __restrict__ ws) {
    __shared__ __align__(16) unsigned short wt[128 * 64];    // 16 KB
    __shared__ __align__(16) unsigned short ht[112 * 64];    // 14 KB
    const int tid = threadIdx.x;
    const int pt = blockIdx.x, b = blockIdx.y;
    const int p0 = pt * 112;
    const float mn1 = ws[SCAL_OFF + 0], sc1 = ws[SCAL_OFF + 1];
    const float inv1 = ws[SCAL_OFF + 2];
    const unsigned short* qw1 = (const unsigned short*)(ws + QW1_OFF);
    const float* xb = x + (size_t)b * C_IN * HW;
    float* outb = out + (size_t)b * C_TOT * HW;

    const int o = tid & 7, q = tid >> 3;
    const int wv = tid >> 6, g = (tid >> 4) & 3, r4 = tid & 15;

    f32x4 acc[2][7];
#pragma unroll
    for (int i = 0; i < 2; ++i)
#pragma unroll
        for (int j = 0; j < 7; ++j) acc[i][j] = f32x4{0.f, 0.f, 0.f, 0.f};

    f32x4 xreg[8];
    if (tid < 224) {
#pragma unroll
        for (int j = 0; j < 8; ++j)
            xreg[j] = *(const f32x4*)(xb + (size_t)(o * 8 + j) * HW + p0 + q * 4);
    }

    for (int ks = 0; ks < 8; ++ks) {
        const float4* wsrc = (const float4*)(qw1 + (size_t)ks * 8192);
        float4* wdst = (float4*)wt;
#pragma unroll
        for (int i = 0; i < 4; ++i) wdst[tid + i * 256] = wsrc[tid + i * 256];

        if (tid < 224) {
            const int ci0 = ks * 64 + o * 8;
            float vv[8][4];
#pragma unroll
            for (int j = 0; j < 8; ++j) {
                const f32x4 v = xreg[j];
                // fused concat copy: out[:, :512] = x (raw, NT — never re-read)
                __builtin_nontemporal_store(v, (f32x4*)(outb + (size_t)(ci0 + j) * HW + p0 + q * 4));
                const float A = ws[BNA_OFF + ci0 + j], Bc = ws[BNB_OFF + ci0 + j];
                vv[j][0] = fmaf(rintf((fmaxf(fmaf(v.x, A, Bc), 0.f) - mn1) * inv1), sc1, mn1);
                vv[j][1] = fmaf(rintf((fmaxf(fmaf(v.y, A, Bc), 0.f) - mn1) * inv1), sc1, mn1);
                vv[j][2] = fmaf(rintf((fmaxf(fmaf(v.z, A, Bc), 0.f) - mn1) * inv1), sc1, mn1);
                vv[j][3] = fmaf(rintf((fmaxf(fmaf(v.w, A, Bc), 0.f) - mn1) * inv1), sc1, mn1);
            }
            if (ks < 7) {
                const int ci0n = (ks + 1) * 64 + o * 8;
#pragma unroll
                for (int j = 0; j < 8; ++j)
                    xreg[j] = *(const f32x4*)(xb + (size_t)(ci0n + j) * HW + p0 + q * 4);
            }
#pragma unroll
            for (int r = 0; r < 4; ++r) {
                const int p = q * 4 + r;
                uint4 pk;
                pk.x = f2bf(vv[0][r]) | (f2bf(vv[1][r]) << 16);
                pk.y = f2bf(vv[2][r]) | (f2bf(vv[3][r]) << 16);
                pk.z = f2bf(vv[4][r]) | (f2bf(vv[5][r]) << 16);
                pk.w = f2bf(vv[6][r]) | (f2bf(vv[7][r]) << 16);
                *(uint4*)&ht[p * 64 + ((o ^ (p & 7)) << 3)] = pk;
            }
        }
        __syncthreads();

#pragma unroll
        for (int ksub = 0; ksub < 2; ++ksub) {
            const int kk = ksub * 4 + g;
            bf16x8 af[2], bfr[7];
#pragma unroll
            for (int ct = 0; ct < 2; ++ct) {
                const int co = wv * 32 + ct * 16 + r4;
                af[ct] = *(const bf16x8*)&wt[co * 64 + ((kk ^ (co & 7)) << 3)];
            }
#pragma unroll
            for (int pf = 0; pf < 7; ++pf) {
                const int p = pf * 16 + r4;
                bfr[pf] = *(const bf16x8*)&ht[p * 64 + ((kk ^ (p & 7)) << 3)];
            }
#pragma unroll
            for (int ct = 0; ct < 2; ++ct)
#pragma unroll
                for (int pf = 0; pf < 7; ++pf)
                    acc[ct][pf] = __builtin_amdgcn_mfma_f32_16x16x32_bf16(af[ct], bfr[pf], acc[ct][pf], 0, 0, 0);
        }
        __syncthreads();
    }

    unsigned short* hb = (unsigned short*)(ws + H2_OFF) + (size_t)b * C_MID * HW;
#pragma unroll
    for (int ct = 0; ct < 2; ++ct) {
        const int co0 = wv * 32 + ct * 16 + g * 4;
#pragma unroll
        for (int pf = 0; pf < 7; ++pf) {
            const int p = p0 + pf * 16 + r4;
#pragma unroll
            for (int r = 0; r < 4; ++r)
                hb[(size_t)(co0 + r) * HW + p] = (unsigned short)f2bf(acc[ct][pf][r]);
        }
    }

#pragma unroll
    for (int ct = 0; ct < 2; ++ct)
#pragma unroll
        for (int r = 0; r < 4; ++r) {
            float s = 0.f, mn = INFINITY, mx = -INFINITY;
#pragma unroll
            for (int pf = 0; pf < 7; ++pf) {
                const float v = acc[ct][pf][r];
                s += v; mn = fminf(mn, v); mx = fmaxf(mx, v);
            }
#pragma unroll
            for (int m = 1; m < 16; m <<= 1) {
                s  += __shfl_xor(s, m, 64);
                mn  = fminf(mn, __shfl_xor(mn, m, 64));
                mx  = fmaxf(mx, __shfl_xor(mx, m, 64));
            }
            if (r4 == 0) {
                const int co = wv * 32 + ct * 16 + g * 4 + r;
                float* dst = ws + RP_OFF + (((size_t)co * 64 + b) * 7 + pt) * 3;
                dst[0] = s; dst[1] = mn; dst[2] = mx;
            }
        }
}

// ---------- K3: combine RBN partials -> per-channel affine + h3 endpoints (PART2) ----------
__global__ __launch_bounds__(64) void k_rbn_combine(float* __restrict__ ws) {
    const int c = blockIdx.x, t = threadIdx.x;
    const int ch = t >> 2, sub = t & 3;
    const int b = ch * 4 + sub;
    const float* rp = ws + RP_OFF + ((size_t)c * 64 + b) * 21;
    float s = 0.f, mn = INFINITY, mx = -INFINITY;
#pragma unroll
    for (int pt = 0; pt < 7; ++pt) {
        s += rp[pt * 3 + 0];
        mn = fminf(mn, rp[pt * 3 + 1]);
        mx = fmaxf(mx, rp[pt * 3 + 2]);
    }
#pragma unroll
    for (int m = 1; m < 4; m <<= 1) {
        s  += __shfl_xor(s, m, 64);
        mn  = fminf(mn, __shfl_xor(mn, m, 64));
        mx  = fmaxf(mx, __shfl_xor(mx, m, 64));
    }
    float smx = mx, smn = mn, stot = s, gmn = mn, gmx = mx;
#pragma unroll
    for (int m = 4; m < 64; m <<= 1) {
        smx  += __shfl_xor(smx, m, 64);
        smn  += __shfl_xor(smn, m, 64);
        stot += __shfl_xor(stot, m, 64);
        gmn   = fminf(gmn, __shfl_xor(gmn, m, 64));
        gmx   = fmaxf(gmx, __shfl_xor(gmx, m, 64));
    }
    if (t == 0) {
        const float mm = smx * (1.f / 16.f), mnm = smn * (1.f / 16.f);
        const float mean = stot / 50176.f;
        const double PI_D = 3.14159265358979323846;
        const double sfd = 0.175 * (1.0 + sqrt(PI_D * log(4.0))) / sqrt(2.0 * log(3136.0));
        const float scale = 1.f / ((mm - mnm) * (float)sfd + 1e-5f);
        const float A  = scale * ws[QRW_OFF + c];
        const float Bc = ws[QRB_OFF + c] - mean * A;
        ws[A2_OFF + c] = A; ws[B2_OFF + c] = Bc;
        const float v1 = A * gmn + Bc, v2 = A * gmx + Bc;
        ws[PART2_OFF + c * 2 + 0] = fmaxf(0.f, fminf(v1, v2));
        ws[PART2_OFF + c * 2 + 1] = fmaxf(0.f, fmaxf(v1, v2));
    }
}

// ---------- K4: 3x3 conv via MFMA implicit im2col, 256 threads, h2 bf16, h3 range from PART2 ----------
__global__ __launch_bounds__(256, 2) void k_conv2(float* __restrict__ out, const float* __restrict__ ws) {
    __shared__ __align__(16) unsigned short lact[7 * 30 * 128];   // 52.5 KB
    __shared__ float sra[128], srb[128];
    __shared__ float s_mn3, s_mx3, s_sc3, s_inv3;
    const int tid = threadIdx.x;
    const int pt = blockIdx.x, b = blockIdx.y;
    const int y0 = pt * 4;

    if (tid < 128) { sra[tid] = ws[PART2_OFF + tid * 2]; srb[tid] = ws[PART2_OFF + tid * 2 + 1]; }
    __syncthreads();
    for (int off = 64; off > 0; off >>= 1) {
        if (tid < off) { sra[tid] = fminf(sra[tid], sra[tid + off]); srb[tid] = fmaxf(srb[tid], srb[tid + off]); }
        __syncthreads();
    }
    if (tid == 0) {
        const float mn3 = sra[0], mx3 = srb[0];
        const float sc = fmaxf((mx3 - mn3) / 255.f, 1e-8f);
        s_mn3 = mn3; s_mx3 = mx3; s_sc3 = sc; s_inv3 = 1.f / sc;
    }
    {
        const uint4 z = {0u, 0u, 0u, 0u};
        uint4* lp = (uint4*)lact;
        for (int i = tid; i < 3360; i += 256) lp[i] = z;
    }
    __syncthreads();
    const float mn3 = s_mn3, mx3 = s_mx3, sc3 = s_sc3, inv3 = s_inv3;

    const unsigned short* h2b = (const unsigned short*)(ws + H2_OFF) + (size_t)b * C_MID * HW;
    for (int task = tid; task < 672; task += 256) {
        const int oct = task / 42, rem = task % 42, r = rem / 7, xq = rem % 7;
        const int gy = y0 - 1 + r;
        if (gy < 0 || gy > 27) continue;
        float vv[8][4];
#pragma unroll
        for (int j = 0; j < 8; ++j) {
            const int ci = oct * 8 + j;
            const ushort4 v = *(const ushort4*)(h2b + (size_t)ci * HW + gy * 28 + xq * 4);
            const float A = ws[A2_OFF + ci], Bc = ws[B2_OFF + ci];
            vv[j][0] = qact(fmaxf(0.f, fmaf(bf2f(v.x), A, Bc)), mn3, mx3, inv3, sc3);
            vv[j][1] = qact(fmaxf(0.f, fmaf(bf2f(v.y), A, Bc)), mn3, mx3, inv3, sc3);
            vv[j][2] = qact(fmaxf(0.f, fmaf(bf2f(v.z), A, Bc)), mn3, mx3, inv3, sc3);
            vv[j][3] = qact(fmaxf(0.f, fmaf(bf2f(v.w), A, Bc)), mn3, mx3, inv3, sc3);
        }
#pragma unroll
        for (int xi = 0; xi < 4; ++xi) {
            const int col = xq * 4 + xi + 1;
            const int phys = (oct + col) & 15;
            uint4 pk;
            pk.x = f2bf(vv[0][xi]) | (f2bf(vv[1][xi]) << 16);
            pk.y = f2bf(vv[2][xi]) | (f2bf(vv[3][xi]) << 16);
            pk.z = f2bf(vv[4][xi]) | (f2bf(vv[5][xi]) << 16);
            pk.w = f2bf(vv[6][xi]) | (f2bf(vv[7][xi]) << 16);
            *(uint4*)&lact[((r * 30 + col) * 16 + phys) * 8] = pk;
        }
    }
    __syncthreads();

    const int wv = tid >> 6, lane = tid & 63, r4 = lane & 15, g = lane >> 4;
    int py[2], px[2];
#pragma unroll
    for (int i = 0; i < 2; ++i) {
        const int p = (wv * 2 + i) * 16 + r4;
        py[i] = p / 28; px[i] = p % 28;
    }
    f32x4 acc[2][2];
#pragma unroll
    for (int ct = 0; ct < 2; ++ct)
#pragma unroll
        for (int i = 0; i < 2; ++i) acc[ct][i] = f32x4{0.f, 0.f, 0.f, 0.f};

    const unsigned short* qw2 = (const unsigned short*)(ws + QW2_OFF);
    for (int tap = 0; tap < 9; ++tap) {
        const int dy = tap / 3, dx = tap % 3;
        bf16x8 afr[2][4];
#pragma unroll
        for (int ct = 0; ct < 2; ++ct)
#pragma unroll
            for (int c4 = 0; c4 < 4; ++c4) {
                const int co = ct * 16 + r4;
                afr[ct][c4] = *(const bf16x8*)&qw2[(size_t)co * 1152 + tap * 128 + c4 * 32 + g * 8];
            }
#pragma unroll
        for (int c4 = 0; c4 < 4; ++c4) {
            bf16x8 bfr[2];
#pragma unroll
            for (int i = 0; i < 2; ++i) {
                const int row = py[i] + dy, col = px[i] + dx;
                const int phys = (c4 * 4 + g + col) & 15;
                bfr[i] = *(const bf16x8*)&lact[((row * 30 + col) * 16 + phys) * 8];
            }
#pragma unroll
            for (int ct = 0; ct < 2; ++ct)
#pragma unroll
                for (int i = 0; i < 2; ++i)
                    acc[ct][i] = __builtin_amdgcn_mfma_f32_16x16x32_bf16(afr[ct][c4], bfr[i], acc[ct][i], 0, 0, 0);
        }
    }

#pragma unroll
    for (int ct = 0; ct < 2; ++ct)
#pragma unroll
        for (int i = 0; i < 2; ++i) {
            const int pf = wv * 2 + i;
            if (pf < 7) {
                const int p = pf * 16 + r4;
#pragma unroll
                for (int r = 0; r < 4; ++r) {
                    const int co = ct * 16 + g * 4 + r;
                    out[((size_t)b * C_TOT + 512 + co) * HW + y0 * 28 + p] = acc[ct][i][r];
                }
            }
        }
}

extern "C" void kernel_launch(void* const* d_in, const int* in_sizes, int n_in,
                              void* d_out, int out_size, void* d_ws, size_t ws_size,
                              hipStream_t stream) {
    const float* x       = (const float*)d_in[0];
    const float* bn1_w   = (const float*)d_in[1];
    const float* bn1_b   = (const float*)d_in[2];
    const float* conv1_w = (const float*)d_in[3];
    const float* rbn_w   = (const float*)d_in[4];
    const float* rbn_b   = (const float*)d_in[5];
    const float* conv2_w = (const float*)d_in[6];
    float* out = (float*)d_out;
    float* ws  = (float*)d_ws;   // needs ~27 MB

    k_stats<<<4136, 256, 0, stream>>>(x, conv1_w, conv2_w, ws);
    k_prep<<<42, 256, 0, stream>>>(conv1_w, conv2_w, bn1_w, bn1_b, rbn_w, rbn_b, ws);
    k_conv1<<<dim3(7, 64), 256, 0, stream>>>(x, out, ws);
    k_rbn_combine<<<128, 64, 0, stream>>>(ws);
    k_conv2<<<dim3(7, 64), 256, 0, stream>>>(out, ws);
}